// Round 1
// baseline (1192.245 us; speedup 1.0000x reference)
//
#include <hip/hip_runtime.h>

// GQA attention forward. Inputs/outputs FP32 (per reference); internal compute
// bf16 MFMA. BS=4 SEQ=1024 DM=4096 HQ=32 HKV=8 DK=DV=128.
// R4: attn_kernel restructured: 128 q-rows/block, Q hoisted to registers,
// mask in prefetched registers (no LDS), K/V double-buffered with mid-iter
// staging issue (1 barrier per k-tile, was 3), XOR-swizzled P buffer,
// defer-max rescale skip, deferred l-reduce, setprio around MFMA clusters.

using ushort = unsigned short;
typedef __attribute__((ext_vector_type(8))) short short8;   // 8 bf16 (4 VGPRs)
typedef __attribute__((ext_vector_type(4))) short short4v;  // 4 bf16
typedef __attribute__((ext_vector_type(4))) float f32x4;    // MFMA C/D

__device__ __forceinline__ ushort f2bf(float x) {  // RNE fp32->bf16
  unsigned int u = __float_as_uint(x);
  u += 0x7FFFu + ((u >> 16) & 1u);
  return (ushort)(u >> 16);
}
__device__ __forceinline__ float bf2f(ushort h) {
  return __uint_as_float(((unsigned int)h) << 16);
}

__device__ __forceinline__ void async_copy16(const void* g, void* l) {
  // LDS dest = wave-uniform base + lane*16 (pass uniform l).
  __builtin_amdgcn_global_load_lds((const __attribute__((address_space(1))) void*)g,
                                   (__attribute__((address_space(3))) void*)l, 16, 0, 0);
}

// ---------------------------------------------------------------------------
// fp32 -> bf16 elementwise, 4 elems/thread
// ---------------------------------------------------------------------------
__global__ __launch_bounds__(256)
void cvt_f32_bf16(const float* __restrict__ in, ushort* __restrict__ out, int n4) {
  const int i = blockIdx.x * 256 + threadIdx.x;
  if (i < n4) {
    const float4 f = ((const float4*)in)[i];
    short4v v;
    v[0] = (short)f2bf(f.x); v[1] = (short)f2bf(f.y);
    v[2] = (short)f2bf(f.z); v[3] = (short)f2bf(f.w);
    ((short4v*)out)[i] = v;
  }
}

// ---------------------------------------------------------------------------
// Weight transpose+convert: B fp32 [4096][N] -> Bt bf16 [N][4096]
// ---------------------------------------------------------------------------
__global__ __launch_bounds__(256)
void transpose_cvt(const float* __restrict__ B, ushort* __restrict__ Bt, int N) {
  __shared__ ushort t[64][72];  // +8 pad breaks bank conflicts
  const int n0 = blockIdx.x * 64, k0 = blockIdx.y * 64;
  const int tid = threadIdx.x;
  const int r = tid >> 3, c8 = (tid & 7) * 8;
#pragma unroll
  for (int p = 0; p < 2; p++) {
    const float* src = B + (size_t)(k0 + r + p * 32) * N + n0 + c8;
    const float4 f0 = *(const float4*)src;
    const float4 f1 = *(const float4*)(src + 4);
    ushort* d = &t[r + p * 32][c8];
    d[0] = f2bf(f0.x); d[1] = f2bf(f0.y); d[2] = f2bf(f0.z); d[3] = f2bf(f0.w);
    d[4] = f2bf(f1.x); d[5] = f2bf(f1.y); d[6] = f2bf(f1.z); d[7] = f2bf(f1.w);
  }
  __syncthreads();
#pragma unroll
  for (int p = 0; p < 2; p++) {
    const int n = r + p * 32;
    short8 o;
#pragma unroll
    for (int j = 0; j < 8; j++) o[j] = (short)t[c8 + j][n];
    *(short8*)(Bt + (size_t)(n0 + n) * 4096 + k0 + c8) = o;
  }
}

// ---------------------------------------------------------------------------
// GEMM C = A[4096x4096] * Bt[Nx4096]^T, bf16 MFMA, fp32 accum. K=4096.
// j-remap: wave's n-columns = wn2 + (j&1)*16 + (j>>1)*64 + l16 so acc[i][j]
// and acc[i][j+2] hold the RoPE pair (d, d+64) in-register.
// MODE 0: C fp32 row-major [M][N] (O-projection -> d_out)
// MODE 1: Q head-major bf16 [b][32][s][128], RoPE+scale fused
// MODE 4 (AF32): fused KV; n0<1024 -> K bf16 [b][8][s][128] with RoPE;
//                n0>=1024 -> V^T bf16 [b][8][128][s]
// ---------------------------------------------------------------------------
template <int MODE, bool AF32>
__global__ __launch_bounds__(256, 2)
void gemm_bt(const float* __restrict__ Af, const float* __restrict__ A2f,
             const ushort* __restrict__ Abf, const ushort* __restrict__ Bt,
             ushort* __restrict__ C, ushort* __restrict__ C2,
             float* __restrict__ Cf, const int* __restrict__ posp,
             int N, float scale) {
  constexpr int K = 4096;
  __shared__ alignas(16) ushort As[128 * 32];
  __shared__ alignas(16) ushort Bs[128 * 32];
  const int tid = threadIdx.x;
  const int wave = tid >> 6, lane = tid & 63;
  const int quad = lane >> 4, l16 = lane & 15;
  const int m0 = blockIdx.y * 128, n0 = blockIdx.x * 128;
  const int wm = (wave & 1) * 64, wn2 = (wave >> 1) * 32;

  const size_t aoff = (size_t)(m0 + wave * 16 + (lane >> 2)) * K + (lane & 3) * 8;
  const float* gAf = nullptr;
  const ushort* gAb = nullptr;
  if constexpr (AF32) {
    const float* Ause = Af;
    if constexpr (MODE == 4) {
      if (n0 >= 1024) Ause = A2f;  // V half reads `value`
    }
    gAf = Ause + aoff;
  } else {
    gAb = Abf + aoff;
  }
  const ushort* gB = Bt + (size_t)(n0 + wave * 16 + (lane >> 2)) * K + (lane & 3) * 8;
  ushort* lA = As + wave * 512;  // wave-uniform LDS bases
  ushort* lB = Bs + wave * 512;
  constexpr size_t rstep = (size_t)64 * K;

  f32x4 acc[4][4] = {};

  for (int kt = 0; kt < K; kt += 32) {
    if constexpr (AF32) {
      const float4 a0 = *(const float4*)(gAf + kt);
      const float4 a1 = *(const float4*)(gAf + kt + 4);
      const float4 b0 = *(const float4*)(gAf + rstep + kt);
      const float4 b1 = *(const float4*)(gAf + rstep + kt + 4);
      short8 v0, v1;
      v0[0] = (short)f2bf(a0.x); v0[1] = (short)f2bf(a0.y);
      v0[2] = (short)f2bf(a0.z); v0[3] = (short)f2bf(a0.w);
      v0[4] = (short)f2bf(a1.x); v0[5] = (short)f2bf(a1.y);
      v0[6] = (short)f2bf(a1.z); v0[7] = (short)f2bf(a1.w);
      v1[0] = (short)f2bf(b0.x); v1[1] = (short)f2bf(b0.y);
      v1[2] = (short)f2bf(b0.z); v1[3] = (short)f2bf(b0.w);
      v1[4] = (short)f2bf(b1.x); v1[5] = (short)f2bf(b1.y);
      v1[6] = (short)f2bf(b1.z); v1[7] = (short)f2bf(b1.w);
      *(short8*)(lA + lane * 8) = v0;
      *(short8*)(lA + 2048 + lane * 8) = v1;
    } else {
      async_copy16(gAb + kt, lA);
      async_copy16(gAb + rstep + kt, lA + 2048);
    }
    async_copy16(gB + kt, lB);
    async_copy16(gB + rstep + kt, lB + 2048);
    __syncthreads();
    short8 af[4], bfrag[4];
#pragma unroll
    for (int i = 0; i < 4; i++) {
      af[i] = *(const short8*)(As + (wm + i * 16 + l16) * 32 + quad * 8);
      bfrag[i] = *(const short8*)(
          Bs + (wn2 + (i & 1) * 16 + (i >> 1) * 64 + l16) * 32 + quad * 8);
    }
#pragma unroll
    for (int i = 0; i < 4; i++)
#pragma unroll
      for (int j = 0; j < 4; j++)
        acc[i][j] = __builtin_amdgcn_mfma_f32_16x16x32_bf16(af[i], bfrag[j],
                                                            acc[i][j], 0, 0, 0);
    __syncthreads();
  }

  // ---------------- epilogue ----------------
  if constexpr (MODE == 0) {
#pragma unroll
    for (int i = 0; i < 4; i++)
#pragma unroll
      for (int j = 0; j < 4; j++) {
        const int n = n0 + wn2 + (j & 1) * 16 + (j >> 1) * 64 + l16;
        const int mb = m0 + wm + i * 16 + quad * 4;
#pragma unroll
        for (int r = 0; r < 4; r++)
          Cf[(size_t)(mb + r) * N + n] = acc[i][j][r] * scale;
      }
  } else {
    const bool kv_v = (MODE == 4) && (n0 >= 1024);
    if (!kv_v) {
      // RoPE epilogue (Q: MODE 1, K: MODE 4 low half)
      const int pos0 = posp[0];
      const int h = (MODE == 1) ? (n0 >> 7) : (n0 >> 7);
      const int NH = (MODE == 1) ? 32 : 8;
      constexpr float lgbase = -0.20762050593045983f;  // -log2(10000)/64
      float invf[2];
      invf[0] = exp2f((float)(wn2 + l16) * lgbase);
      invf[1] = exp2f((float)(wn2 + 16 + l16) * lgbase);
#pragma unroll
      for (int i = 0; i < 4; i++) {
#pragma unroll
        for (int r = 0; r < 4; r++) {
          const int m = m0 + wm + i * 16 + quad * 4 + r;
          const int s = m & 1023, bb = m >> 10;
          const float p = (float)(s + pos0);
          ushort* row = C + (((size_t)bb * NH + h) * 1024 + s) * 128;
#pragma unroll
          for (int jj = 0; jj < 2; jj++) {
            float sn, cs;
            sincosf(p * invf[jj], &sn, &cs);
            const float x1 = acc[i][jj][r] * scale;
            const float x2 = acc[i][jj + 2][r] * scale;
            const int dlo = wn2 + jj * 16 + l16;
            row[dlo] = f2bf(x1 * cs - x2 * sn);
            row[dlo + 64] = f2bf(x2 * cs + x1 * sn);
          }
        }
      }
    } else {
      // V half: no RoPE, transposed write [b][8][128][s]
      const int hh = (n0 - 1024) >> 7;
#pragma unroll
      for (int i = 0; i < 4; i++)
#pragma unroll
        for (int j = 0; j < 4; j++) {
          const int d = wn2 + (j & 1) * 16 + (j >> 1) * 64 + l16;
          const int mb = m0 + wm + i * 16 + quad * 4;
#pragma unroll
          for (int r = 0; r < 4; r++) {
            const int m = mb + r;
            const int bb = m >> 10, s = m & 1023;
            C2[(((size_t)bb * 8 + hh) * 128 + d) * 1024 + s] = f2bf(acc[i][j][r]);
          }
        }
    }
  }
}

// ---------------------------------------------------------------------------
// Flash attention, R4 structure.
// Block = 128 q-rows (4 waves x 32), 16 k-tiles of 64. One barrier per k-tile:
//   top barrier (drains prev-issued staging) -> mask reg loads -> QK MFMA
//   -> issue K/V staging for kt+64 into ping-pong buffers -> softmax (defer-max,
//   partial-l) -> P to swizzled LDS -> PV MFMA.
// Q hoisted to registers via one-time LDS stage. LDS = 80 KB (2 blocks/CU).
// ---------------------------------------------------------------------------
__global__ __launch_bounds__(256, 2)
void attn_kernel(const ushort* __restrict__ Qh, const ushort* __restrict__ Kh,
                 const ushort* __restrict__ Vt, const ushort* __restrict__ Mk,
                 ushort* __restrict__ Oh) {
  // [0,8K): Ks0  [8K,16K): Ks1  [16K,24K): Vs0  [24K,32K): Vs1  [32K,40K): Ps
  __shared__ alignas(16) ushort smem[40960];  // 80 KB
  ushort* const Ks0 = smem;
  ushort* const Ks1 = smem + 8192;
  ushort* const Vs0 = smem + 16384;
  ushort* const Vs1 = smem + 24576;
  ushort* const Ps = smem + 32768;
  ushort* const Qtmp = smem + 16384;  // overlays Vs0+Vs1 (32 KB), pre-loop only

  const int b = blockIdx.z, h = blockIdx.y;
  const int q0 = blockIdx.x * 128;
  const int hkv = h >> 2;
  const int tid = threadIdx.x;
  const int wave = tid >> 6, lane = tid & 63;
  const int quad = lane >> 4, l16 = lane & 15;
  const int vr = lane >> 3;
  const int vkc = (lane & 7) ^ (vr & 7);

  const ushort* Qg = Qh + (((size_t)b * 32 + h) * 1024 + q0) * 128;
  const ushort* Kg = Kh + ((size_t)b * 8 + hkv) * (size_t)(1024 * 128);
  const ushort* Vg = Vt + ((size_t)b * 8 + hkv) * (size_t)(128 * 1024);
  const ushort* Mg = Mk + ((size_t)b * 1024 + q0) * 1024;

  // ---- prologue: stage this wave's Q rows + K(0); hoist Q to registers ----
#pragma unroll
  for (int c = 0; c < 8; c++) {  // Q 128x128, wave stages its own 32 rows
    const int i = wave * 8 + c;
    const int row = i * 4 + quad;
    const int kc = l16 ^ ((c & 3) * 4 + quad);  // key = row&15
    async_copy16(Qg + (size_t)row * 128 + kc * 8, Qtmp + i * 512);
  }
#pragma unroll
  for (int c = 0; c < 4; c++) {  // K(0) 64x128 -> Ks0
    const int i = wave * 4 + c;
    const int row = i * 4 + quad;
    const int kc = l16 ^ (c * 4 + quad);
    async_copy16(Kg + (size_t)row * 128 + kc * 8, Ks0 + i * 512);
  }
  __asm__ volatile("s_waitcnt vmcnt(0)" ::: "memory");  // own Q rows landed
  short8 qreg[2][4];
#pragma unroll
  for (int t = 0; t < 2; t++)
#pragma unroll
    for (int ks = 0; ks < 4; ks++)
      qreg[t][ks] = *(const short8*)(Qtmp + (size_t)(wave * 32 + t * 16 + l16) * 128 +
                                     (((ks * 4 + quad) ^ l16) * 8));
  __syncthreads();  // all waves done with Qtmp before V0 staging overwrites it
#pragma unroll
  for (int c = 0; c < 4; c++) {  // V(0) 128x64 (V^T layout) -> Vs0
    const int i = wave * 4 + c;
    async_copy16(Vg + (size_t)(i * 8 + vr) * 1024 + vkc * 8, Vs0 + i * 512);
  }

  float m_i[2][4], l_p[2][4];
#pragma unroll
  for (int t = 0; t < 2; t++)
#pragma unroll
    for (int r = 0; r < 4; r++) { m_i[t][r] = -1e30f; l_p[t][r] = 0.0f; }
  f32x4 acc[2][8] = {};

  ushort* const PW = Ps + wave * 2048;  // 32 rows x 64 cols bf16, XOR-swizzled

  for (int kt = 0; kt < 1024; kt += 64) {
    const int it = kt >> 6;
    ushort* const Kc = (it & 1) ? Ks1 : Ks0;
    ushort* const Vc = (it & 1) ? Vs1 : Vs0;
    ushort* const Kn = (it & 1) ? Ks0 : Ks1;
    ushort* const Vn = (it & 1) ? Vs0 : Vs1;
    __syncthreads();  // single barrier: staged tile kt now visible everywhere

    // mask loads for this tile -> registers (consumed after QK; latency hidden)
    ushort mr[2][4][4];
#pragma unroll
    for (int t = 0; t < 2; t++)
#pragma unroll
      for (int nt = 0; nt < 4; nt++)
#pragma unroll
        for (int r = 0; r < 4; r++)
          mr[t][nt][r] = Mg[(size_t)(wave * 32 + t * 16 + quad * 4 + r) * 1024 +
                            kt + nt * 16 + l16];

    // S = Q K^T, both row-tiles share each K fragment read
    f32x4 s0[4] = {}, s1[4] = {};
    __builtin_amdgcn_s_setprio(1);
#pragma unroll
    for (int ks = 0; ks < 4; ks++) {
      const int ko = ((ks * 4 + quad) ^ l16) * 8;
#pragma unroll
      for (int nt = 0; nt < 4; nt++) {
        const short8 bk = *(const short8*)(Kc + (size_t)(nt * 16 + l16) * 128 + ko);
        s0[nt] = __builtin_amdgcn_mfma_f32_16x16x32_bf16(qreg[0][ks], bk, s0[nt], 0, 0, 0);
        s1[nt] = __builtin_amdgcn_mfma_f32_16x16x32_bf16(qreg[1][ks], bk, s1[nt], 0, 0, 0);
      }
    }
    __builtin_amdgcn_s_setprio(0);

    // issue next tile's staging into the ping-pong buffers (drained at next
    // loop-top barrier; overlaps softmax+PV below)
    if (kt < 960) {
#pragma unroll
      for (int c = 0; c < 4; c++) {
        const int i = wave * 4 + c;
        const int row = i * 4 + quad;
        const int kc = l16 ^ (c * 4 + quad);
        async_copy16(Kg + (size_t)(kt + 64 + row) * 128 + kc * 8, Kn + i * 512);
      }
#pragma unroll
      for (int c = 0; c < 4; c++) {
        const int i = wave * 4 + c;
        async_copy16(Vg + (size_t)(i * 8 + vr) * 1024 + kt + 64 + vkc * 8, Vn + i * 512);
      }
    }

    // additive mask (C layout: row = quad*4+r, col = l16)
#pragma unroll
    for (int nt = 0; nt < 4; nt++)
#pragma unroll
      for (int r = 0; r < 4; r++) {
        s0[nt][r] += bf2f(mr[0][nt][r]);
        s1[nt][r] += bf2f(mr[1][nt][r]);
      }

    // row max (16-lane reduce) + defer-max vote
    float mx[2][4];
    int need = 0;
#pragma unroll
    for (int t = 0; t < 2; t++)
#pragma unroll
      for (int r = 0; r < 4; r++) {
        float v = t ? fmaxf(fmaxf(s1[0][r], s1[1][r]), fmaxf(s1[2][r], s1[3][r]))
                    : fmaxf(fmaxf(s0[0][r], s0[1][r]), fmaxf(s0[2][r], s0[3][r]));
#pragma unroll
        for (int off = 1; off < 16; off <<= 1) v = fmaxf(v, __shfl_xor(v, off));
        mx[t][r] = v;
        need |= (v > m_i[t][r] + 8.0f) ? 1 : 0;
      }
    if (__any(need)) {  // rescale path (rare after warm-up: defer-max THR=8)
#pragma unroll
      for (int t = 0; t < 2; t++)
#pragma unroll
        for (int r = 0; r < 4; r++) {
          const float mnew = fmaxf(m_i[t][r], mx[t][r]);
          const float al = __expf(m_i[t][r] - mnew);
          m_i[t][r] = mnew;
          l_p[t][r] *= al;
#pragma unroll
          for (int dt = 0; dt < 8; dt++) acc[t][dt][r] *= al;
        }
    }

    // exp (bounded by e^8 under defer) + per-lane partial row sums + P -> LDS.
    // P element (row,col) at row*64 + (col ^ (((row>>1)&7)*8)): conflict-free
    // for both the quad-row u16 writes and the b128 A-fragment reads.
#pragma unroll
    for (int t = 0; t < 2; t++)
#pragma unroll
      for (int r = 0; r < 4; r++) {
        const int prow = t * 16 + quad * 4 + r;
        const int key8 = ((prow >> 1) & 7) * 8;
        float sum = 0.0f;
#pragma unroll
        for (int nt = 0; nt < 4; nt++) {
          const float sv = t ? s1[nt][r] : s0[nt][r];
          const float p = __expf(sv - m_i[t][r]);
          sum += p;
          PW[prow * 64 + ((nt * 16 + l16) ^ key8)] = f2bf(p);
        }
        l_p[t][r] += sum;
      }
    __asm__ volatile("s_waitcnt lgkmcnt(0)" ::: "memory");

    // O += P V (A: P[m=l16][k], B: V^T[d][k]); V fragment shared by both tiles
    __builtin_amdgcn_s_setprio(1);
#pragma unroll
    for (int kk = 0; kk < 2; kk++) {
      const int pslot = ((kk * 4 + quad) ^ (l16 >> 1)) * 8;  // key = row>>1 & 7
      const short8 ap0 = *(const short8*)(PW + (size_t)l16 * 64 + pslot);
      const short8 ap1 = *(const short8*)(PW + (size_t)(16 + l16) * 64 + pslot);
#pragma unroll
      for (int dt = 0; dt < 8; dt++) {
        const int vo = ((kk * 4 + quad) ^ (l16 & 7)) * 8;
        const short8 bv = *(const short8*)(Vc + (size_t)(dt * 16 + l16) * 64 + vo);
        acc[0][dt] = __builtin_amdgcn_mfma_f32_16x16x32_bf16(ap0, bv, acc[0][dt], 0, 0, 0);
        acc[1][dt] = __builtin_amdgcn_mfma_f32_16x16x32_bf16(ap1, bv, acc[1][dt], 0, 0, 0);
      }
    }
    __builtin_amdgcn_s_setprio(0);
  }

  // epilogue: finish deferred l reduce, normalize, store Oh[b*1024+s][h*128+d]
  ushort* Og = Oh + ((size_t)b * 1024 + q0 + wave * 32) * 4096 + h * 128;
#pragma unroll
  for (int t = 0; t < 2; t++)
#pragma unroll
    for (int r = 0; r < 4; r++) {
      float l = l_p[t][r];
#pragma unroll
      for (int off = 1; off < 16; off <<= 1) l += __shfl_xor(l, off);
      const float inv = 1.0f / l;
#pragma unroll
      for (int dt = 0; dt < 8; dt++)
        Og[(size_t)(t * 16 + quad * 4 + r) * 4096 + dt * 16 + l16] =
            f2bf(acc[t][dt][r] * inv);
    }
}

// ---------------------------------------------------------------------------
extern "C" void kernel_launch(void* const* d_in, const int* in_sizes, int n_in,
                              void* d_out, int out_size, void* d_ws, size_t ws_size,
                              hipStream_t stream) {
  (void)in_sizes; (void)n_in; (void)out_size; (void)ws_size;
  const float* query = (const float*)d_in[0];
  const float* key = (const float*)d_in[1];
  const float* value = (const float*)d_in[2];
  const float* mask = (const float*)d_in[3];
  const float* wq = (const float*)d_in[4];
  const float* wk = (const float*)d_in[5];
  const float* wv = (const float*)d_in[6];
  const float* wo = (const float*)d_in[7];
  const int* pos = (const int*)d_in[8];
  float* out = (float*)d_out;

  char* ws = (char*)d_ws;
  const size_t MB = 1024 * 1024;
  // Region reuse plan (peak 104 MiB):
  ushort* qb = (ushort*)(ws + 0 * MB);     // [0,32): qb -> Khb[0,8)+Vtb[8,16)
  ushort* Khb = (ushort*)(ws + 0 * MB);
  ushort* Vtb = (ushort*)(ws + 8 * MB);
  ushort* wqT = (ushort*)(ws + 32 * MB);   // [32,64): wqT -> wkvT[32,48) -> Ohb[32,64)
  ushort* wkvT = (ushort*)(ws + 32 * MB);
  ushort* Ohb = (ushort*)(ws + 32 * MB);
  ushort* Qhb = (ushort*)(ws + 64 * MB);   // [64,96): Qhb -> woT
  ushort* woT = (ushort*)(ws + 64 * MB);
  ushort* mbf = (ushort*)(ws + 96 * MB);   // [96,104)

  dim3 blk(256);
  cvt_f32_bf16<<<dim3(4096), blk, 0, stream>>>(mask, mbf, 1048576);
  cvt_f32_bf16<<<dim3(16384), blk, 0, stream>>>(query, qb, 4194304);

  transpose_cvt<<<dim3(64, 64), blk, 0, stream>>>(wq, wqT, 4096);
  // Q projection, scale + RoPE fused
  gemm_bt<1, false><<<dim3(32, 32), blk, 0, stream>>>(
      nullptr, nullptr, qb, wqT, Qhb, nullptr, nullptr, pos, 4096,
      0.08838834764831845f);

  transpose_cvt<<<dim3(16, 64), blk, 0, stream>>>(wk, wkvT, 1024);
  transpose_cvt<<<dim3(16, 64), blk, 0, stream>>>(wv, wkvT + (size_t)1024 * 4096, 1024);
  // fused K+V projection (K gets RoPE; V written transposed)
  gemm_bt<4, true><<<dim3(16, 32), blk, 0, stream>>>(
      key, value, nullptr, wkvT, Khb, Vtb, nullptr, pos, 2048, 1.0f);

  attn_kernel<<<dim3(8, 32, 4), blk, 0, stream>>>(Qhb, Khb, Vtb, mbf, Ohb);

  transpose_cvt<<<dim3(64, 64), blk, 0, stream>>>(wo, woT, 4096);  // Qhb dead
  // output projection -> fp32 d_out
  gemm_bt<0, false><<<dim3(32, 32), blk, 0, stream>>>(
      nullptr, nullptr, Ohb, woT, nullptr, nullptr, out, pos, 4096, 1.0f);
}

// Round 3
// 962.064 us; speedup vs baseline: 1.2393x; 1.2393x over previous
//
#include <hip/hip_runtime.h>

// GQA attention forward. Inputs/outputs FP32 (per reference); internal compute
// bf16 MFMA. BS=4 SEQ=1024 DM=4096 HQ=32 HKV=8 D_K=DV=128.
// R6 == R5 with the LDS size bug fixed (smem was 34816, must be 36864: P
// buffer for waves 2-3 was out of bounds). Structure: 64 q-rows/block
// (16 rows/wave, no spill), single barrier per k-tile, ping-pong K/V staged
// mid-iteration, Q hoisted to registers, mask prefetched to registers,
// XOR-swizzled P buffer, defer-max, deferred l-reduce, setprio around MFMA.

using ushort = unsigned short;
typedef __attribute__((ext_vector_type(8))) short short8;   // 8 bf16 (4 VGPRs)
typedef __attribute__((ext_vector_type(4))) short short4v;  // 4 bf16
typedef __attribute__((ext_vector_type(4))) float f32x4;    // MFMA C/D

__device__ __forceinline__ ushort f2bf(float x) {  // RNE fp32->bf16
  unsigned int u = __float_as_uint(x);
  u += 0x7FFFu + ((u >> 16) & 1u);
  return (ushort)(u >> 16);
}
__device__ __forceinline__ float bf2f(ushort h) {
  return __uint_as_float(((unsigned int)h) << 16);
}

__device__ __forceinline__ void async_copy16(const void* g, void* l) {
  // LDS dest = wave-uniform base + lane*16 (pass uniform l).
  __builtin_amdgcn_global_load_lds((const __attribute__((address_space(1))) void*)g,
                                   (__attribute__((address_space(3))) void*)l, 16, 0, 0);
}

// ---------------------------------------------------------------------------
// fp32 -> bf16 elementwise, 4 elems/thread
// ---------------------------------------------------------------------------
__global__ __launch_bounds__(256)
void cvt_f32_bf16(const float* __restrict__ in, ushort* __restrict__ out, int n4) {
  const int i = blockIdx.x * 256 + threadIdx.x;
  if (i < n4) {
    const float4 f = ((const float4*)in)[i];
    short4v v;
    v[0] = (short)f2bf(f.x); v[1] = (short)f2bf(f.y);
    v[2] = (short)f2bf(f.z); v[3] = (short)f2bf(f.w);
    ((short4v*)out)[i] = v;
  }
}

// ---------------------------------------------------------------------------
// Weight transpose+convert: B fp32 [4096][N] -> Bt bf16 [N][4096]
// ---------------------------------------------------------------------------
__global__ __launch_bounds__(256)
void transpose_cvt(const float* __restrict__ B, ushort* __restrict__ Bt, int N) {
  __shared__ ushort t[64][72];  // +8 pad breaks bank conflicts
  const int n0 = blockIdx.x * 64, k0 = blockIdx.y * 64;
  const int tid = threadIdx.x;
  const int r = tid >> 3, c8 = (tid & 7) * 8;
#pragma unroll
  for (int p = 0; p < 2; p++) {
    const float* src = B + (size_t)(k0 + r + p * 32) * N + n0 + c8;
    const float4 f0 = *(const float4*)src;
    const float4 f1 = *(const float4*)(src + 4);
    ushort* d = &t[r + p * 32][c8];
    d[0] = f2bf(f0.x); d[1] = f2bf(f0.y); d[2] = f2bf(f0.z); d[3] = f2bf(f0.w);
    d[4] = f2bf(f1.x); d[5] = f2bf(f1.y); d[6] = f2bf(f1.z); d[7] = f2bf(f1.w);
  }
  __syncthreads();
#pragma unroll
  for (int p = 0; p < 2; p++) {
    const int n = r + p * 32;
    short8 o;
#pragma unroll
    for (int j = 0; j < 8; j++) o[j] = (short)t[c8 + j][n];
    *(short8*)(Bt + (size_t)(n0 + n) * 4096 + k0 + c8) = o;
  }
}

// ---------------------------------------------------------------------------
// GEMM C = A[4096x4096] * Bt[Nx4096]^T, bf16 MFMA, fp32 accum. K=4096.
// j-remap: wave's n-columns = wn2 + (j&1)*16 + (j>>1)*64 + l16 so acc[i][j]
// and acc[i][j+2] hold the RoPE pair (d, d+64) in-register.
// MODE 0: C fp32 row-major [M][N] (O-projection -> d_out)
// MODE 1: Q head-major bf16 [b][32][s][128], RoPE+scale fused
// MODE 4 (AF32): fused KV; n0<1024 -> K bf16 [b][8][s][128] with RoPE;
//                n0>=1024 -> V^T bf16 [b][8][128][s]
// ---------------------------------------------------------------------------
template <int MODE, bool AF32>
__global__ __launch_bounds__(256, 2)
void gemm_bt(const float* __restrict__ Af, const float* __restrict__ A2f,
             const ushort* __restrict__ Abf, const ushort* __restrict__ Bt,
             ushort* __restrict__ C, ushort* __restrict__ C2,
             float* __restrict__ Cf, const int* __restrict__ posp,
             int N, float scale) {
  constexpr int K = 4096;
  __shared__ alignas(16) ushort As[128 * 32];
  __shared__ alignas(16) ushort Bs[128 * 32];
  const int tid = threadIdx.x;
  const int wave = tid >> 6, lane = tid & 63;
  const int quad = lane >> 4, l16 = lane & 15;
  const int m0 = blockIdx.y * 128, n0 = blockIdx.x * 128;
  const int wm = (wave & 1) * 64, wn2 = (wave >> 1) * 32;

  const size_t aoff = (size_t)(m0 + wave * 16 + (lane >> 2)) * K + (lane & 3) * 8;
  const float* gAf = nullptr;
  const ushort* gAb = nullptr;
  if constexpr (AF32) {
    const float* Ause = Af;
    if constexpr (MODE == 4) {
      if (n0 >= 1024) Ause = A2f;  // V half reads `value`
    }
    gAf = Ause + aoff;
  } else {
    gAb = Abf + aoff;
  }
  const ushort* gB = Bt + (size_t)(n0 + wave * 16 + (lane >> 2)) * K + (lane & 3) * 8;
  ushort* lA = As + wave * 512;  // wave-uniform LDS bases
  ushort* lB = Bs + wave * 512;
  constexpr size_t rstep = (size_t)64 * K;

  f32x4 acc[4][4] = {};

  for (int kt = 0; kt < K; kt += 32) {
    if constexpr (AF32) {
      const float4 a0 = *(const float4*)(gAf + kt);
      const float4 a1 = *(const float4*)(gAf + kt + 4);
      const float4 b0 = *(const float4*)(gAf + rstep + kt);
      const float4 b1 = *(const float4*)(gAf + rstep + kt + 4);
      short8 v0, v1;
      v0[0] = (short)f2bf(a0.x); v0[1] = (short)f2bf(a0.y);
      v0[2] = (short)f2bf(a0.z); v0[3] = (short)f2bf(a0.w);
      v0[4] = (short)f2bf(a1.x); v0[5] = (short)f2bf(a1.y);
      v0[6] = (short)f2bf(a1.z); v0[7] = (short)f2bf(a1.w);
      v1[0] = (short)f2bf(b0.x); v1[1] = (short)f2bf(b0.y);
      v1[2] = (short)f2bf(b0.z); v1[3] = (short)f2bf(b0.w);
      v1[4] = (short)f2bf(b1.x); v1[5] = (short)f2bf(b1.y);
      v1[6] = (short)f2bf(b1.z); v1[7] = (short)f2bf(b1.w);
      *(short8*)(lA + lane * 8) = v0;
      *(short8*)(lA + 2048 + lane * 8) = v1;
    } else {
      async_copy16(gAb + kt, lA);
      async_copy16(gAb + rstep + kt, lA + 2048);
    }
    async_copy16(gB + kt, lB);
    async_copy16(gB + rstep + kt, lB + 2048);
    __syncthreads();
    short8 af[4], bfrag[4];
#pragma unroll
    for (int i = 0; i < 4; i++) {
      af[i] = *(const short8*)(As + (wm + i * 16 + l16) * 32 + quad * 8);
      bfrag[i] = *(const short8*)(
          Bs + (wn2 + (i & 1) * 16 + (i >> 1) * 64 + l16) * 32 + quad * 8);
    }
#pragma unroll
    for (int i = 0; i < 4; i++)
#pragma unroll
      for (int j = 0; j < 4; j++)
        acc[i][j] = __builtin_amdgcn_mfma_f32_16x16x32_bf16(af[i], bfrag[j],
                                                            acc[i][j], 0, 0, 0);
    __syncthreads();
  }

  // ---------------- epilogue ----------------
  if constexpr (MODE == 0) {
#pragma unroll
    for (int i = 0; i < 4; i++)
#pragma unroll
      for (int j = 0; j < 4; j++) {
        const int n = n0 + wn2 + (j & 1) * 16 + (j >> 1) * 64 + l16;
        const int mb = m0 + wm + i * 16 + quad * 4;
#pragma unroll
        for (int r = 0; r < 4; r++)
          Cf[(size_t)(mb + r) * N + n] = acc[i][j][r] * scale;
      }
  } else {
    const bool kv_v = (MODE == 4) && (n0 >= 1024);
    if (!kv_v) {
      // RoPE epilogue (Q: MODE 1, K: MODE 4 low half)
      const int pos0 = posp[0];
      const int h = (MODE == 1) ? (n0 >> 7) : (n0 >> 7);
      const int NH = (MODE == 1) ? 32 : 8;
      constexpr float lgbase = -0.20762050593045983f;  // -log2(10000)/64
      float invf[2];
      invf[0] = exp2f((float)(wn2 + l16) * lgbase);
      invf[1] = exp2f((float)(wn2 + 16 + l16) * lgbase);
#pragma unroll
      for (int i = 0; i < 4; i++) {
#pragma unroll
        for (int r = 0; r < 4; r++) {
          const int m = m0 + wm + i * 16 + quad * 4 + r;
          const int s = m & 1023, bb = m >> 10;
          const float p = (float)(s + pos0);
          ushort* row = C + (((size_t)bb * NH + h) * 1024 + s) * 128;
#pragma unroll
          for (int jj = 0; jj < 2; jj++) {
            float sn, cs;
            sincosf(p * invf[jj], &sn, &cs);
            const float x1 = acc[i][jj][r] * scale;
            const float x2 = acc[i][jj + 2][r] * scale;
            const int dlo = wn2 + jj * 16 + l16;
            row[dlo] = f2bf(x1 * cs - x2 * sn);
            row[dlo + 64] = f2bf(x2 * cs + x1 * sn);
          }
        }
      }
    } else {
      // V half: no RoPE, transposed write [b][8][128][s]
      const int hh = (n0 - 1024) >> 7;
#pragma unroll
      for (int i = 0; i < 4; i++)
#pragma unroll
        for (int j = 0; j < 4; j++) {
          const int d = wn2 + (j & 1) * 16 + (j >> 1) * 64 + l16;
          const int mb = m0 + wm + i * 16 + quad * 4;
#pragma unroll
          for (int r = 0; r < 4; r++) {
            const int m = mb + r;
            const int bb = m >> 10, s = m & 1023;
            C2[(((size_t)bb * 8 + hh) * 128 + d) * 1024 + s] = f2bf(acc[i][j][r]);
          }
        }
    }
  }
}

// ---------------------------------------------------------------------------
// Flash attention, R6.
// Block = 64 q-rows (4 waves x 16), 16 k-tiles of 64. One barrier per k-tile:
//   top barrier (drains prev-issued staging) -> mask reg loads -> QK MFMA
//   -> issue K/V staging for kt+64 into ping-pong buffers -> softmax
//   (defer-max, deferred-l) -> P to swizzled LDS -> PV MFMA.
// Q hoisted to registers once. LDS layout (ushort offsets):
//   Ks0 [0,8192) Ks1 [8192,16384) Vs0 [16384,24576) Vs1 [24576,32768)
//   Ps [32768,36864)  -> total 36864 ushorts = 72 KB -> 2 blocks/CU.
// ---------------------------------------------------------------------------
__global__ __launch_bounds__(256, 2)
void attn_kernel(const ushort* __restrict__ Qh, const ushort* __restrict__ Kh,
                 const ushort* __restrict__ Vt, const ushort* __restrict__ Mk,
                 ushort* __restrict__ Oh) {
  __shared__ alignas(16) ushort smem[36864];  // 72 KB
  ushort* const Ks0 = smem;
  ushort* const Ks1 = smem + 8192;
  ushort* const Vs0 = smem + 16384;
  ushort* const Vs1 = smem + 24576;
  ushort* const Ps = smem + 32768;   // 4 waves x 16x64 = 4096 ushorts (8 KB)
  ushort* const Qtmp = smem + 16384;  // overlays Vs0 (8192 ushorts), pre-loop only

  const int b = blockIdx.z, h = blockIdx.y;
  const int q0 = blockIdx.x * 64;
  const int hkv = h >> 2;
  const int tid = threadIdx.x;
  const int wave = tid >> 6, lane = tid & 63;
  const int quad = lane >> 4, l16 = lane & 15;
  const int vr = lane >> 3;
  const int vkc = (lane & 7) ^ (vr & 7);

  const ushort* Qg = Qh + (((size_t)b * 32 + h) * 1024 + q0) * 128;
  const ushort* Kg = Kh + ((size_t)b * 8 + hkv) * (size_t)(1024 * 128);
  const ushort* Vg = Vt + ((size_t)b * 8 + hkv) * (size_t)(128 * 1024);
  const ushort* Mg = Mk + ((size_t)b * 1024 + q0) * 1024;

  // ---- prologue: stage Q (64x128) + K(0); hoist Q to registers ----
#pragma unroll
  for (int c = 0; c < 4; c++) {  // Q, swizzled: chunk j of row r at slot j^(r&15)
    const int i = wave * 4 + c;
    const int row = i * 4 + quad;
    const int kc = l16 ^ (c * 4 + quad);  // c*4+quad == row&15
    async_copy16(Qg + (size_t)row * 128 + kc * 8, Qtmp + i * 512);
  }
#pragma unroll
  for (int c = 0; c < 4; c++) {  // K(0) 64x128 -> Ks0, same swizzle
    const int i = wave * 4 + c;
    const int row = i * 4 + quad;
    const int kc = l16 ^ (c * 4 + quad);
    async_copy16(Kg + (size_t)row * 128 + kc * 8, Ks0 + i * 512);
  }
  __asm__ volatile("s_waitcnt vmcnt(0)" ::: "memory");  // own Q rows landed
  short8 qreg[4];
#pragma unroll
  for (int ks = 0; ks < 4; ks++)
    qreg[ks] = *(const short8*)(Qtmp + (size_t)(wave * 16 + l16) * 128 +
                                (((ks * 4 + quad) ^ l16) * 8));
  __syncthreads();  // all waves done with Qtmp before V0 staging overwrites it
#pragma unroll
  for (int c = 0; c < 4; c++) {  // V(0) 128x64 (V^T layout) -> Vs0
    const int i = wave * 4 + c;
    async_copy16(Vg + (size_t)(i * 8 + vr) * 1024 + vkc * 8, Vs0 + i * 512);
  }

  float m_i[4], l_p[4];
#pragma unroll
  for (int r = 0; r < 4; r++) { m_i[r] = -1e30f; l_p[r] = 0.0f; }
  f32x4 acc[8] = {};

  ushort* const PW = Ps + wave * 1024;  // 16 rows x 64 cols bf16, XOR-swizzled

  for (int kt = 0; kt < 1024; kt += 64) {
    const int it = kt >> 6;
    ushort* const Kc = (it & 1) ? Ks1 : Ks0;
    ushort* const Vc = (it & 1) ? Vs1 : Vs0;
    ushort* const Kn = (it & 1) ? Ks0 : Ks1;
    ushort* const Vn = (it & 1) ? Vs0 : Vs1;
    __syncthreads();  // single barrier: staged tile kt now visible everywhere

    // mask loads for this tile -> registers (consumed after QK; latency hidden)
    ushort mr[4][4];
#pragma unroll
    for (int nt = 0; nt < 4; nt++)
#pragma unroll
      for (int r = 0; r < 4; r++)
        mr[nt][r] = Mg[(size_t)(wave * 16 + quad * 4 + r) * 1024 +
                       kt + nt * 16 + l16];

    // S = Q K^T
    f32x4 s[4] = {};
    __builtin_amdgcn_s_setprio(1);
#pragma unroll
    for (int ks = 0; ks < 4; ks++) {
      const int ko = ((ks * 4 + quad) ^ l16) * 8;
#pragma unroll
      for (int nt = 0; nt < 4; nt++) {
        const short8 bk = *(const short8*)(Kc + (size_t)(nt * 16 + l16) * 128 + ko);
        s[nt] = __builtin_amdgcn_mfma_f32_16x16x32_bf16(qreg[ks], bk, s[nt], 0, 0, 0);
      }
    }
    __builtin_amdgcn_s_setprio(0);

    // issue next tile's staging into the ping-pong buffers (drained at next
    // loop-top barrier; overlaps softmax+PV below)
    if (kt < 960) {
#pragma unroll
      for (int c = 0; c < 4; c++) {
        const int i = wave * 4 + c;
        const int row = i * 4 + quad;
        const int kc = l16 ^ (c * 4 + quad);
        async_copy16(Kg + (size_t)(kt + 64 + row) * 128 + kc * 8, Kn + i * 512);
      }
#pragma unroll
      for (int c = 0; c < 4; c++) {
        const int i = wave * 4 + c;
        async_copy16(Vg + (size_t)(i * 8 + vr) * 1024 + kt + 64 + vkc * 8, Vn + i * 512);
      }
    }

    // additive mask (C layout: row = quad*4+r, col = l16)
#pragma unroll
    for (int nt = 0; nt < 4; nt++)
#pragma unroll
      for (int r = 0; r < 4; r++) s[nt][r] += bf2f(mr[nt][r]);

    // row max (16-lane reduce) + defer-max vote
    float mx[4];
    int need = 0;
#pragma unroll
    for (int r = 0; r < 4; r++) {
      float v = fmaxf(fmaxf(s[0][r], s[1][r]), fmaxf(s[2][r], s[3][r]));
#pragma unroll
      for (int off = 1; off < 16; off <<= 1) v = fmaxf(v, __shfl_xor(v, off));
      mx[r] = v;
      need |= (v > m_i[r] + 8.0f) ? 1 : 0;
    }
    if (__any(need)) {  // rescale path (rare after warm-up: defer-max THR=8)
#pragma unroll
      for (int r = 0; r < 4; r++) {
        const float mnew = fmaxf(m_i[r], mx[r]);
        const float al = __expf(m_i[r] - mnew);
        m_i[r] = mnew;
        l_p[r] *= al;
#pragma unroll
        for (int dt = 0; dt < 8; dt++) acc[dt][r] *= al;
      }
    }

    // exp (bounded by e^8 under defer) + per-lane partial row sums + P -> LDS.
    // P element (row,col) at row*64 + (col ^ (((row>>1)&7)*8)): conflict-free
    // (measured 0 in R4) for quad-row u16 writes and b128 A-fragment reads.
#pragma unroll
    for (int r = 0; r < 4; r++) {
      const int prow = quad * 4 + r;
      const int key8 = ((prow >> 1) & 7) * 8;
      float sum = 0.0f;
#pragma unroll
      for (int nt = 0; nt < 4; nt++) {
        const float p = __expf(s[nt][r] - m_i[r]);
        sum += p;
        PW[prow * 64 + ((nt * 16 + l16) ^ key8)] = f2bf(p);
      }
      l_p[r] += sum;
    }
    __asm__ volatile("s_waitcnt lgkmcnt(0)" ::: "memory");

    // O += P V (A: P[m=l16][k], B: V^T[d][k])
    __builtin_amdgcn_s_setprio(1);
#pragma unroll
    for (int kk = 0; kk < 2; kk++) {
      const int pslot = ((kk * 4 + quad) ^ (l16 >> 1)) * 8;  // key = (row>>1)&7
      const short8 ap = *(const short8*)(PW + (size_t)l16 * 64 + pslot);
#pragma unroll
      for (int dt = 0; dt < 8; dt++) {
        const int vo = ((kk * 4 + quad) ^ (l16 & 7)) * 8;
        const short8 bv = *(const short8*)(Vc + (size_t)(dt * 16 + l16) * 64 + vo);
        acc[dt] = __builtin_amdgcn_mfma_f32_16x16x32_bf16(ap, bv, acc[dt], 0, 0, 0);
      }
    }
    __builtin_amdgcn_s_setprio(0);
  }

  // epilogue: finish deferred l reduce, normalize, store Oh[b*1024+s][h*128+d]
  ushort* Og = Oh + ((size_t)b * 1024 + q0 + wave * 16) * 4096 + h * 128;
#pragma unroll
  for (int r = 0; r < 4; r++) {
    float l = l_p[r];
#pragma unroll
    for (int off = 1; off < 16; off <<= 1) l += __shfl_xor(l, off);
    const float inv = 1.0f / l;
#pragma unroll
    for (int dt = 0; dt < 8; dt++)
      Og[(size_t)(quad * 4 + r) * 4096 + dt * 16 + l16] = f2bf(acc[dt][r] * inv);
  }
}

// ---------------------------------------------------------------------------
extern "C" void kernel_launch(void* const* d_in, const int* in_sizes, int n_in,
                              void* d_out, int out_size, void* d_ws, size_t ws_size,
                              hipStream_t stream) {
  (void)in_sizes; (void)n_in; (void)out_size; (void)ws_size;
  const float* query = (const float*)d_in[0];
  const float* key = (const float*)d_in[1];
  const float* value = (const float*)d_in[2];
  const float* mask = (const float*)d_in[3];
  const float* wq = (const float*)d_in[4];
  const float* wk = (const float*)d_in[5];
  const float* wv = (const float*)d_in[6];
  const float* wo = (const float*)d_in[7];
  const int* pos = (const int*)d_in[8];
  float* out = (float*)d_out;

  char* ws = (char*)d_ws;
  const size_t MB = 1024 * 1024;
  // Region reuse plan (peak 104 MiB):
  ushort* qb = (ushort*)(ws + 0 * MB);     // [0,32): qb -> Khb[0,8)+Vtb[8,16)
  ushort* Khb = (ushort*)(ws + 0 * MB);
  ushort* Vtb = (ushort*)(ws + 8 * MB);
  ushort* wqT = (ushort*)(ws + 32 * MB);   // [32,64): wqT -> wkvT[32,48) -> Ohb[32,64)
  ushort* wkvT = (ushort*)(ws + 32 * MB);
  ushort* Ohb = (ushort*)(ws + 32 * MB);
  ushort* Qhb = (ushort*)(ws + 64 * MB);   // [64,96): Qhb -> woT
  ushort* woT = (ushort*)(ws + 64 * MB);
  ushort* mbf = (ushort*)(ws + 96 * MB);   // [96,104)

  dim3 blk(256);
  cvt_f32_bf16<<<dim3(4096), blk, 0, stream>>>(mask, mbf, 1048576);
  cvt_f32_bf16<<<dim3(16384), blk, 0, stream>>>(query, qb, 4194304);

  transpose_cvt<<<dim3(64, 64), blk, 0, stream>>>(wq, wqT, 4096);
  // Q projection, scale + RoPE fused
  gemm_bt<1, false><<<dim3(32, 32), blk, 0, stream>>>(
      nullptr, nullptr, qb, wqT, Qhb, nullptr, nullptr, pos, 4096,
      0.08838834764831845f);

  transpose_cvt<<<dim3(16, 64), blk, 0, stream>>>(wk, wkvT, 1024);
  transpose_cvt<<<dim3(16, 64), blk, 0, stream>>>(wv, wkvT + (size_t)1024 * 4096, 1024);
  // fused K+V projection (K gets RoPE; V written transposed)
  gemm_bt<4, true><<<dim3(16, 32), blk, 0, stream>>>(
      key, value, nullptr, wkvT, Khb, Vtb, nullptr, pos, 2048, 1.0f);

  attn_kernel<<<dim3(16, 32, 4), blk, 0, stream>>>(Qhb, Khb, Vtb, mbf, Ohb);

  transpose_cvt<<<dim3(64, 64), blk, 0, stream>>>(wo, woT, 4096);  // Qhb dead
  // output projection -> fp32 d_out
  gemm_bt<0, false><<<dim3(32, 32), blk, 0, stream>>>(
      nullptr, nullptr, Ohb, woT, nullptr, nullptr, out, pos, 4096, 1.0f);
}

// Round 4
// 936.483 us; speedup vs baseline: 1.2731x; 1.0273x over previous
//
#include <hip/hip_runtime.h>

// GQA attention forward. Inputs/outputs FP32 (per reference); internal compute
// bf16 MFMA. BS=4 SEQ=1024 DM=4096 HQ=32 HKV=8 D_K=DV=128.
// R7 = R6 + three micro-optimizations:
//  (1) attn P->bf16 via v_cvt_pk_bf16_f32 (16 f2bf ~80 VALU -> 8 pk + 8 shr)
//  (2) KV GEMM fp32 staging via cvt_pk (16 f2bf -> 8 pk per K-step)
//  (3) attn XCD-chunked block swizzle (64 consecutive blocks share K/V panel;
//      chunk them onto one XCD's L2 instead of round-robin over 8)

using ushort = unsigned short;
typedef __attribute__((ext_vector_type(8))) short short8;   // 8 bf16 (4 VGPRs)
typedef __attribute__((ext_vector_type(4))) short short4v;  // 4 bf16
typedef __attribute__((ext_vector_type(4))) float f32x4;    // MFMA C/D
typedef __attribute__((ext_vector_type(4))) unsigned int uint4v;

__device__ __forceinline__ ushort f2bf(float x) {  // RNE fp32->bf16
  unsigned int u = __float_as_uint(x);
  u += 0x7FFFu + ((u >> 16) & 1u);
  return (ushort)(u >> 16);
}
__device__ __forceinline__ float bf2f(ushort h) {
  return __uint_as_float(((unsigned int)h) << 16);
}
// RNE pack: lo -> bits[15:0], hi -> bits[31:16] (T12; no builtin on gfx950)
__device__ __forceinline__ unsigned int cvt_pk_bf16(float lo, float hi) {
  unsigned int r;
  asm("v_cvt_pk_bf16_f32 %0, %1, %2" : "=v"(r) : "v"(lo), "v"(hi));
  return r;
}

__device__ __forceinline__ void async_copy16(const void* g, void* l) {
  // LDS dest = wave-uniform base + lane*16 (pass uniform l).
  __builtin_amdgcn_global_load_lds((const __attribute__((address_space(1))) void*)g,
                                   (__attribute__((address_space(3))) void*)l, 16, 0, 0);
}

// ---------------------------------------------------------------------------
// fp32 -> bf16 elementwise, 4 elems/thread
// ---------------------------------------------------------------------------
__global__ __launch_bounds__(256)
void cvt_f32_bf16(const float* __restrict__ in, ushort* __restrict__ out, int n4) {
  const int i = blockIdx.x * 256 + threadIdx.x;
  if (i < n4) {
    const float4 f = ((const float4*)in)[i];
    short4v v;
    v[0] = (short)f2bf(f.x); v[1] = (short)f2bf(f.y);
    v[2] = (short)f2bf(f.z); v[3] = (short)f2bf(f.w);
    ((short4v*)out)[i] = v;
  }
}

// ---------------------------------------------------------------------------
// Weight transpose+convert: B fp32 [4096][N] -> Bt bf16 [N][4096]
// ---------------------------------------------------------------------------
__global__ __launch_bounds__(256)
void transpose_cvt(const float* __restrict__ B, ushort* __restrict__ Bt, int N) {
  __shared__ ushort t[64][72];  // +8 pad breaks bank conflicts
  const int n0 = blockIdx.x * 64, k0 = blockIdx.y * 64;
  const int tid = threadIdx.x;
  const int r = tid >> 3, c8 = (tid & 7) * 8;
#pragma unroll
  for (int p = 0; p < 2; p++) {
    const float* src = B + (size_t)(k0 + r + p * 32) * N + n0 + c8;
    const float4 f0 = *(const float4*)src;
    const float4 f1 = *(const float4*)(src + 4);
    ushort* d = &t[r + p * 32][c8];
    d[0] = f2bf(f0.x); d[1] = f2bf(f0.y); d[2] = f2bf(f0.z); d[3] = f2bf(f0.w);
    d[4] = f2bf(f1.x); d[5] = f2bf(f1.y); d[6] = f2bf(f1.z); d[7] = f2bf(f1.w);
  }
  __syncthreads();
#pragma unroll
  for (int p = 0; p < 2; p++) {
    const int n = r + p * 32;
    short8 o;
#pragma unroll
    for (int j = 0; j < 8; j++) o[j] = (short)t[c8 + j][n];
    *(short8*)(Bt + (size_t)(n0 + n) * 4096 + k0 + c8) = o;
  }
}

// ---------------------------------------------------------------------------
// GEMM C = A[4096x4096] * Bt[Nx4096]^T, bf16 MFMA, fp32 accum. K=4096.
// j-remap: wave's n-columns = wn2 + (j&1)*16 + (j>>1)*64 + l16 so acc[i][j]
// and acc[i][j+2] hold the RoPE pair (d, d+64) in-register.
// MODE 0: C fp32 row-major [M][N] (O-projection -> d_out)
// MODE 1: Q head-major bf16 [b][32][s][128], RoPE+scale fused
// MODE 4 (AF32): fused KV; n0<1024 -> K bf16 [b][8][s][128] with RoPE;
//                n0>=1024 -> V^T bf16 [b][8][128][s]
// ---------------------------------------------------------------------------
template <int MODE, bool AF32>
__global__ __launch_bounds__(256, 2)
void gemm_bt(const float* __restrict__ Af, const float* __restrict__ A2f,
             const ushort* __restrict__ Abf, const ushort* __restrict__ Bt,
             ushort* __restrict__ C, ushort* __restrict__ C2,
             float* __restrict__ Cf, const int* __restrict__ posp,
             int N, float scale) {
  constexpr int K = 4096;
  __shared__ alignas(16) ushort As[128 * 32];
  __shared__ alignas(16) ushort Bs[128 * 32];
  const int tid = threadIdx.x;
  const int wave = tid >> 6, lane = tid & 63;
  const int quad = lane >> 4, l16 = lane & 15;
  const int m0 = blockIdx.y * 128, n0 = blockIdx.x * 128;
  const int wm = (wave & 1) * 64, wn2 = (wave >> 1) * 32;

  const size_t aoff = (size_t)(m0 + wave * 16 + (lane >> 2)) * K + (lane & 3) * 8;
  const float* gAf = nullptr;
  const ushort* gAb = nullptr;
  if constexpr (AF32) {
    const float* Ause = Af;
    if constexpr (MODE == 4) {
      if (n0 >= 1024) Ause = A2f;  // V half reads `value`
    }
    gAf = Ause + aoff;
  } else {
    gAb = Abf + aoff;
  }
  const ushort* gB = Bt + (size_t)(n0 + wave * 16 + (lane >> 2)) * K + (lane & 3) * 8;
  ushort* lA = As + wave * 512;  // wave-uniform LDS bases
  ushort* lB = Bs + wave * 512;
  constexpr size_t rstep = (size_t)64 * K;

  f32x4 acc[4][4] = {};

  for (int kt = 0; kt < K; kt += 32) {
    if constexpr (AF32) {
      const float4 a0 = *(const float4*)(gAf + kt);
      const float4 a1 = *(const float4*)(gAf + kt + 4);
      const float4 b0 = *(const float4*)(gAf + rstep + kt);
      const float4 b1 = *(const float4*)(gAf + rstep + kt + 4);
      uint4v v0, v1;  // cvt_pk: lo->bits[15:0] matches bf16 element order
      v0[0] = cvt_pk_bf16(a0.x, a0.y); v0[1] = cvt_pk_bf16(a0.z, a0.w);
      v0[2] = cvt_pk_bf16(a1.x, a1.y); v0[3] = cvt_pk_bf16(a1.z, a1.w);
      v1[0] = cvt_pk_bf16(b0.x, b0.y); v1[1] = cvt_pk_bf16(b0.z, b0.w);
      v1[2] = cvt_pk_bf16(b1.x, b1.y); v1[3] = cvt_pk_bf16(b1.z, b1.w);
      *(uint4v*)(lA + lane * 8) = v0;
      *(uint4v*)(lA + 2048 + lane * 8) = v1;
    } else {
      async_copy16(gAb + kt, lA);
      async_copy16(gAb + rstep + kt, lA + 2048);
    }
    async_copy16(gB + kt, lB);
    async_copy16(gB + rstep + kt, lB + 2048);
    __syncthreads();
    short8 af[4], bfrag[4];
#pragma unroll
    for (int i = 0; i < 4; i++) {
      af[i] = *(const short8*)(As + (wm + i * 16 + l16) * 32 + quad * 8);
      bfrag[i] = *(const short8*)(
          Bs + (wn2 + (i & 1) * 16 + (i >> 1) * 64 + l16) * 32 + quad * 8);
    }
#pragma unroll
    for (int i = 0; i < 4; i++)
#pragma unroll
      for (int j = 0; j < 4; j++)
        acc[i][j] = __builtin_amdgcn_mfma_f32_16x16x32_bf16(af[i], bfrag[j],
                                                            acc[i][j], 0, 0, 0);
    __syncthreads();
  }

  // ---------------- epilogue ----------------
  if constexpr (MODE == 0) {
#pragma unroll
    for (int i = 0; i < 4; i++)
#pragma unroll
      for (int j = 0; j < 4; j++) {
        const int n = n0 + wn2 + (j & 1) * 16 + (j >> 1) * 64 + l16;
        const int mb = m0 + wm + i * 16 + quad * 4;
#pragma unroll
        for (int r = 0; r < 4; r++)
          Cf[(size_t)(mb + r) * N + n] = acc[i][j][r] * scale;
      }
  } else {
    const bool kv_v = (MODE == 4) && (n0 >= 1024);
    if (!kv_v) {
      // RoPE epilogue (Q: MODE 1, K: MODE 4 low half)
      const int pos0 = posp[0];
      const int h = (MODE == 1) ? (n0 >> 7) : (n0 >> 7);
      const int NH = (MODE == 1) ? 32 : 8;
      constexpr float lgbase = -0.20762050593045983f;  // -log2(10000)/64
      float invf[2];
      invf[0] = exp2f((float)(wn2 + l16) * lgbase);
      invf[1] = exp2f((float)(wn2 + 16 + l16) * lgbase);
#pragma unroll
      for (int i = 0; i < 4; i++) {
#pragma unroll
        for (int r = 0; r < 4; r++) {
          const int m = m0 + wm + i * 16 + quad * 4 + r;
          const int s = m & 1023, bb = m >> 10;
          const float p = (float)(s + pos0);
          ushort* row = C + (((size_t)bb * NH + h) * 1024 + s) * 128;
#pragma unroll
          for (int jj = 0; jj < 2; jj++) {
            float sn, cs;
            sincosf(p * invf[jj], &sn, &cs);
            const float x1 = acc[i][jj][r] * scale;
            const float x2 = acc[i][jj + 2][r] * scale;
            const int dlo = wn2 + jj * 16 + l16;
            row[dlo] = f2bf(x1 * cs - x2 * sn);
            row[dlo + 64] = f2bf(x2 * cs + x1 * sn);
          }
        }
      }
    } else {
      // V half: no RoPE, transposed write [b][8][128][s]
      const int hh = (n0 - 1024) >> 7;
#pragma unroll
      for (int i = 0; i < 4; i++)
#pragma unroll
        for (int j = 0; j < 4; j++) {
          const int d = wn2 + (j & 1) * 16 + (j >> 1) * 64 + l16;
          const int mb = m0 + wm + i * 16 + quad * 4;
#pragma unroll
          for (int r = 0; r < 4; r++) {
            const int m = mb + r;
            const int bb = m >> 10, s = m & 1023;
            C2[(((size_t)bb * 8 + hh) * 128 + d) * 1024 + s] = f2bf(acc[i][j][r]);
          }
        }
    }
  }
}

// ---------------------------------------------------------------------------
// Flash attention, R7.
// Block = 64 q-rows (4 waves x 16), 16 k-tiles of 64. One barrier per k-tile:
//   top barrier (drains prev-issued staging) -> mask reg loads -> QK MFMA
//   -> issue K/V staging for kt+64 into ping-pong buffers -> softmax
//   (defer-max, deferred-l) -> P to swizzled LDS via cvt_pk -> PV MFMA.
// XCD-chunked block swizzle: 64 consecutive blocks share a (b,hkv) K/V panel;
// chunking keeps them on one XCD's L2 (2048 blocks / 8 XCDs = 256-chunks).
// Q hoisted to registers once. LDS layout (ushort offsets):
//   Ks0 [0,8192) Ks1 [8192,16384) Vs0 [16384,24576) Vs1 [24576,32768)
//   Ps [32768,36864)  -> total 36864 ushorts = 72 KB -> 2 blocks/CU.
// ---------------------------------------------------------------------------
__global__ __launch_bounds__(256, 2)
void attn_kernel(const ushort* __restrict__ Qh, const ushort* __restrict__ Kh,
                 const ushort* __restrict__ Vt, const ushort* __restrict__ Mk,
                 ushort* __restrict__ Oh) {
  __shared__ alignas(16) ushort smem[36864];  // 72 KB
  ushort* const Ks0 = smem;
  ushort* const Ks1 = smem + 8192;
  ushort* const Vs0 = smem + 16384;
  ushort* const Vs1 = smem + 24576;
  ushort* const Ps = smem + 32768;   // 4 waves x 16x64 = 4096 ushorts (8 KB)
  ushort* const Qtmp = smem + 16384;  // overlays Vs0 (8192 ushorts), pre-loop only

  // XCD-chunked swizzle (bijective: 2048 = 8 * 256)
  int bid = (blockIdx.z * 32 + blockIdx.y) * 16 + blockIdx.x;
  bid = (bid & 7) * 256 + (bid >> 3);
  const int b = bid >> 9, h = (bid >> 4) & 31;
  const int q0 = (bid & 15) * 64;
  const int hkv = h >> 2;
  const int tid = threadIdx.x;
  const int wave = tid >> 6, lane = tid & 63;
  const int quad = lane >> 4, l16 = lane & 15;
  const int vr = lane >> 3;
  const int vkc = (lane & 7) ^ (vr & 7);

  const ushort* Qg = Qh + (((size_t)b * 32 + h) * 1024 + q0) * 128;
  const ushort* Kg = Kh + ((size_t)b * 8 + hkv) * (size_t)(1024 * 128);
  const ushort* Vg = Vt + ((size_t)b * 8 + hkv) * (size_t)(128 * 1024);
  const ushort* Mg = Mk + ((size_t)b * 1024 + q0) * 1024;

  // ---- prologue: stage Q (64x128) + K(0); hoist Q to registers ----
#pragma unroll
  for (int c = 0; c < 4; c++) {  // Q, swizzled: chunk j of row r at slot j^(r&15)
    const int i = wave * 4 + c;
    const int row = i * 4 + quad;
    const int kc = l16 ^ (c * 4 + quad);  // c*4+quad == row&15
    async_copy16(Qg + (size_t)row * 128 + kc * 8, Qtmp + i * 512);
  }
#pragma unroll
  for (int c = 0; c < 4; c++) {  // K(0) 64x128 -> Ks0, same swizzle
    const int i = wave * 4 + c;
    const int row = i * 4 + quad;
    const int kc = l16 ^ (c * 4 + quad);
    async_copy16(Kg + (size_t)row * 128 + kc * 8, Ks0 + i * 512);
  }
  __asm__ volatile("s_waitcnt vmcnt(0)" ::: "memory");  // own Q rows landed
  short8 qreg[4];
#pragma unroll
  for (int ks = 0; ks < 4; ks++)
    qreg[ks] = *(const short8*)(Qtmp + (size_t)(wave * 16 + l16) * 128 +
                                (((ks * 4 + quad) ^ l16) * 8));
  __syncthreads();  // all waves done with Qtmp before V0 staging overwrites it
#pragma unroll
  for (int c = 0; c < 4; c++) {  // V(0) 128x64 (V^T layout) -> Vs0
    const int i = wave * 4 + c;
    async_copy16(Vg + (size_t)(i * 8 + vr) * 1024 + vkc * 8, Vs0 + i * 512);
  }

  float m_i[4], l_p[4];
#pragma unroll
  for (int r = 0; r < 4; r++) { m_i[r] = -1e30f; l_p[r] = 0.0f; }
  f32x4 acc[8] = {};

  ushort* const PW = Ps + wave * 1024;  // 16 rows x 64 cols bf16, XOR-swizzled

  for (int kt = 0; kt < 1024; kt += 64) {
    const int it = kt >> 6;
    ushort* const Kc = (it & 1) ? Ks1 : Ks0;
    ushort* const Vc = (it & 1) ? Vs1 : Vs0;
    ushort* const Kn = (it & 1) ? Ks0 : Ks1;
    ushort* const Vn = (it & 1) ? Vs0 : Vs1;
    __syncthreads();  // single barrier: staged tile kt now visible everywhere

    // mask loads for this tile -> registers (consumed after QK; latency hidden)
    ushort mr[4][4];
#pragma unroll
    for (int nt = 0; nt < 4; nt++)
#pragma unroll
      for (int r = 0; r < 4; r++)
        mr[nt][r] = Mg[(size_t)(wave * 16 + quad * 4 + r) * 1024 +
                       kt + nt * 16 + l16];

    // S = Q K^T
    f32x4 s[4] = {};
    __builtin_amdgcn_s_setprio(1);
#pragma unroll
    for (int ks = 0; ks < 4; ks++) {
      const int ko = ((ks * 4 + quad) ^ l16) * 8;
#pragma unroll
      for (int nt = 0; nt < 4; nt++) {
        const short8 bk = *(const short8*)(Kc + (size_t)(nt * 16 + l16) * 128 + ko);
        s[nt] = __builtin_amdgcn_mfma_f32_16x16x32_bf16(qreg[ks], bk, s[nt], 0, 0, 0);
      }
    }
    __builtin_amdgcn_s_setprio(0);

    // issue next tile's staging into the ping-pong buffers (drained at next
    // loop-top barrier; overlaps softmax+PV below)
    if (kt < 960) {
#pragma unroll
      for (int c = 0; c < 4; c++) {
        const int i = wave * 4 + c;
        const int row = i * 4 + quad;
        const int kc = l16 ^ (c * 4 + quad);
        async_copy16(Kg + (size_t)(kt + 64 + row) * 128 + kc * 8, Kn + i * 512);
      }
#pragma unroll
      for (int c = 0; c < 4; c++) {
        const int i = wave * 4 + c;
        async_copy16(Vg + (size_t)(i * 8 + vr) * 1024 + kt + 64 + vkc * 8, Vn + i * 512);
      }
    }

    // additive mask (C layout: row = quad*4+r, col = l16)
#pragma unroll
    for (int nt = 0; nt < 4; nt++)
#pragma unroll
      for (int r = 0; r < 4; r++) s[nt][r] += bf2f(mr[nt][r]);

    // row max (16-lane reduce) + defer-max vote
    float mx[4];
    int need = 0;
#pragma unroll
    for (int r = 0; r < 4; r++) {
      float v = fmaxf(fmaxf(s[0][r], s[1][r]), fmaxf(s[2][r], s[3][r]));
#pragma unroll
      for (int off = 1; off < 16; off <<= 1) v = fmaxf(v, __shfl_xor(v, off));
      mx[r] = v;
      need |= (v > m_i[r] + 8.0f) ? 1 : 0;
    }
    if (__any(need)) {  // rescale path (rare after warm-up: defer-max THR=8)
#pragma unroll
      for (int r = 0; r < 4; r++) {
        const float mnew = fmaxf(m_i[r], mx[r]);
        const float al = __expf(m_i[r] - mnew);
        m_i[r] = mnew;
        l_p[r] *= al;
#pragma unroll
        for (int dt = 0; dt < 8; dt++) acc[dt][r] *= al;
      }
    }

    // exp (bounded by e^8 under defer) + per-lane partial row sums + P -> LDS.
    // P->bf16 via v_cvt_pk_bf16_f32 (RNE, 1 inst per 2 vals). P element
    // (row,col) at row*64 + (col ^ (((row>>1)&7)*8)): conflict-free (measured
    // 0 in R4/R6) for quad-row u16 writes and b128 A-fragment reads.
#pragma unroll
    for (int r = 0; r < 4; r++) {
      const int prow = quad * 4 + r;
      const int key8 = ((prow >> 1) & 7) * 8;
      const float p0 = __expf(s[0][r] - m_i[r]);
      const float p1 = __expf(s[1][r] - m_i[r]);
      const float p2 = __expf(s[2][r] - m_i[r]);
      const float p3 = __expf(s[3][r] - m_i[r]);
      l_p[r] += (p0 + p1) + (p2 + p3);
      const unsigned int u01 = cvt_pk_bf16(p0, p1);
      const unsigned int u23 = cvt_pk_bf16(p2, p3);
      ushort* row = PW + prow * 64;
      row[l16 ^ key8] = (ushort)u01;
      row[(16 + l16) ^ key8] = (ushort)(u01 >> 16);
      row[(32 + l16) ^ key8] = (ushort)u23;
      row[(48 + l16) ^ key8] = (ushort)(u23 >> 16);
    }
    __asm__ volatile("s_waitcnt lgkmcnt(0)" ::: "memory");

    // O += P V (A: P[m=l16][k], B: V^T[d][k])
    __builtin_amdgcn_s_setprio(1);
#pragma unroll
    for (int kk = 0; kk < 2; kk++) {
      const int pslot = ((kk * 4 + quad) ^ (l16 >> 1)) * 8;  // key = (row>>1)&7
      const short8 ap = *(const short8*)(PW + (size_t)l16 * 64 + pslot);
#pragma unroll
      for (int dt = 0; dt < 8; dt++) {
        const int vo = ((kk * 4 + quad) ^ (l16 & 7)) * 8;
        const short8 bv = *(const short8*)(Vc + (size_t)(dt * 16 + l16) * 64 + vo);
        acc[dt] = __builtin_amdgcn_mfma_f32_16x16x32_bf16(ap, bv, acc[dt], 0, 0, 0);
      }
    }
    __builtin_amdgcn_s_setprio(0);
  }

  // epilogue: finish deferred l reduce, normalize, store Oh[b*1024+s][h*128+d]
  ushort* Og = Oh + ((size_t)b * 1024 + q0 + wave * 16) * 4096 + h * 128;
#pragma unroll
  for (int r = 0; r < 4; r++) {
    float l = l_p[r];
#pragma unroll
    for (int off = 1; off < 16; off <<= 1) l += __shfl_xor(l, off);
    const float inv = 1.0f / l;
#pragma unroll
    for (int dt = 0; dt < 8; dt++)
      Og[(size_t)(quad * 4 + r) * 4096 + dt * 16 + l16] = f2bf(acc[dt][r] * inv);
  }
}

// ---------------------------------------------------------------------------
extern "C" void kernel_launch(void* const* d_in, const int* in_sizes, int n_in,
                              void* d_out, int out_size, void* d_ws, size_t ws_size,
                              hipStream_t stream) {
  (void)in_sizes; (void)n_in; (void)out_size; (void)ws_size;
  const float* query = (const float*)d_in[0];
  const float* key = (const float*)d_in[1];
  const float* value = (const float*)d_in[2];
  const float* mask = (const float*)d_in[3];
  const float* wq = (const float*)d_in[4];
  const float* wk = (const float*)d_in[5];
  const float* wv = (const float*)d_in[6];
  const float* wo = (const float*)d_in[7];
  const int* pos = (const int*)d_in[8];
  float* out = (float*)d_out;

  char* ws = (char*)d_ws;
  const size_t MB = 1024 * 1024;
  // Region reuse plan (peak 104 MiB):
  ushort* qb = (ushort*)(ws + 0 * MB);     // [0,32): qb -> Khb[0,8)+Vtb[8,16)
  ushort* Khb = (ushort*)(ws + 0 * MB);
  ushort* Vtb = (ushort*)(ws + 8 * MB);
  ushort* wqT = (ushort*)(ws + 32 * MB);   // [32,64): wqT -> wkvT[32,48) -> Ohb[32,64)
  ushort* wkvT = (ushort*)(ws + 32 * MB);
  ushort* Ohb = (ushort*)(ws + 32 * MB);
  ushort* Qhb = (ushort*)(ws + 64 * MB);   // [64,96): Qhb -> woT
  ushort* woT = (ushort*)(ws + 64 * MB);
  ushort* mbf = (ushort*)(ws + 96 * MB);   // [96,104)

  dim3 blk(256);
  cvt_f32_bf16<<<dim3(4096), blk, 0, stream>>>(mask, mbf, 1048576);
  cvt_f32_bf16<<<dim3(16384), blk, 0, stream>>>(query, qb, 4194304);

  transpose_cvt<<<dim3(64, 64), blk, 0, stream>>>(wq, wqT, 4096);
  // Q projection, scale + RoPE fused
  gemm_bt<1, false><<<dim3(32, 32), blk, 0, stream>>>(
      nullptr, nullptr, qb, wqT, Qhb, nullptr, nullptr, pos, 4096,
      0.08838834764831845f);

  transpose_cvt<<<dim3(16, 64), blk, 0, stream>>>(wk, wkvT, 1024);
  transpose_cvt<<<dim3(16, 64), blk, 0, stream>>>(wv, wkvT + (size_t)1024 * 4096, 1024);
  // fused K+V projection (K gets RoPE; V written transposed)
  gemm_bt<4, true><<<dim3(16, 32), blk, 0, stream>>>(
      key, value, nullptr, wkvT, Khb, Vtb, nullptr, pos, 2048, 1.0f);

  attn_kernel<<<dim3(16, 32, 4), blk, 0, stream>>>(Qhb, Khb, Vtb, mbf, Ohb);

  transpose_cvt<<<dim3(64, 64), blk, 0, stream>>>(wo, woT, 4096);  // Qhb dead
  // output projection -> fp32 d_out
  gemm_bt<0, false><<<dim3(32, 32), blk, 0, stream>>>(
      nullptr, nullptr, Ohb, woT, nullptr, nullptr, out, pos, 4096, 1.0f);
}

// Round 5
// 932.691 us; speedup vs baseline: 1.2783x; 1.0041x over previous
//
#include <hip/hip_runtime.h>

// GQA attention forward. Inputs/outputs FP32 (per reference); internal compute
// bf16 MFMA. BS=4 SEQ=1024 DM=4096 HQ=32 HKV=8 D_K=DV=128.
// R8 = R7 + gemm_bt restructured to single-barrier ping-pong (T3-minimum):
// double-buffered 32 KB LDS, loop-top barrier drains tile kt (latency hidden
// under tile kt-1 compute), tile kt+1 staging issued before the MFMA cluster.
// AF32 path: fp32 A-loads issued pre-MFMA, cvt_pk+ds_write sunk post-MFMA
// (T14 split). Attn unchanged from R7.

using ushort = unsigned short;
typedef __attribute__((ext_vector_type(8))) short short8;   // 8 bf16 (4 VGPRs)
typedef __attribute__((ext_vector_type(4))) short short4v;  // 4 bf16
typedef __attribute__((ext_vector_type(4))) float f32x4;    // MFMA C/D
typedef __attribute__((ext_vector_type(4))) unsigned int uint4v;

__device__ __forceinline__ ushort f2bf(float x) {  // RNE fp32->bf16
  unsigned int u = __float_as_uint(x);
  u += 0x7FFFu + ((u >> 16) & 1u);
  return (ushort)(u >> 16);
}
__device__ __forceinline__ float bf2f(ushort h) {
  return __uint_as_float(((unsigned int)h) << 16);
}
// RNE pack: lo -> bits[15:0], hi -> bits[31:16] (T12; no builtin on gfx950)
__device__ __forceinline__ unsigned int cvt_pk_bf16(float lo, float hi) {
  unsigned int r;
  asm("v_cvt_pk_bf16_f32 %0, %1, %2" : "=v"(r) : "v"(lo), "v"(hi));
  return r;
}

__device__ __forceinline__ void async_copy16(const void* g, void* l) {
  // LDS dest = wave-uniform base + lane*16 (pass uniform l).
  __builtin_amdgcn_global_load_lds((const __attribute__((address_space(1))) void*)g,
                                   (__attribute__((address_space(3))) void*)l, 16, 0, 0);
}

// ---------------------------------------------------------------------------
// fp32 -> bf16 elementwise, 4 elems/thread
// ---------------------------------------------------------------------------
__global__ __launch_bounds__(256)
void cvt_f32_bf16(const float* __restrict__ in, ushort* __restrict__ out, int n4) {
  const int i = blockIdx.x * 256 + threadIdx.x;
  if (i < n4) {
    const float4 f = ((const float4*)in)[i];
    short4v v;
    v[0] = (short)f2bf(f.x); v[1] = (short)f2bf(f.y);
    v[2] = (short)f2bf(f.z); v[3] = (short)f2bf(f.w);
    ((short4v*)out)[i] = v;
  }
}

// ---------------------------------------------------------------------------
// Weight transpose+convert: B fp32 [4096][N] -> Bt bf16 [N][4096]
// ---------------------------------------------------------------------------
__global__ __launch_bounds__(256)
void transpose_cvt(const float* __restrict__ B, ushort* __restrict__ Bt, int N) {
  __shared__ ushort t[64][72];  // +8 pad breaks bank conflicts
  const int n0 = blockIdx.x * 64, k0 = blockIdx.y * 64;
  const int tid = threadIdx.x;
  const int r = tid >> 3, c8 = (tid & 7) * 8;
#pragma unroll
  for (int p = 0; p < 2; p++) {
    const float* src = B + (size_t)(k0 + r + p * 32) * N + n0 + c8;
    const float4 f0 = *(const float4*)src;
    const float4 f1 = *(const float4*)(src + 4);
    ushort* d = &t[r + p * 32][c8];
    d[0] = f2bf(f0.x); d[1] = f2bf(f0.y); d[2] = f2bf(f0.z); d[3] = f2bf(f0.w);
    d[4] = f2bf(f1.x); d[5] = f2bf(f1.y); d[6] = f2bf(f1.z); d[7] = f2bf(f1.w);
  }
  __syncthreads();
#pragma unroll
  for (int p = 0; p < 2; p++) {
    const int n = r + p * 32;
    short8 o;
#pragma unroll
    for (int j = 0; j < 8; j++) o[j] = (short)t[c8 + j][n];
    *(short8*)(Bt + (size_t)(n0 + n) * 4096 + k0 + c8) = o;
  }
}

// ---------------------------------------------------------------------------
// GEMM C = A[4096x4096] * Bt[Nx4096]^T, bf16 MFMA, fp32 accum. K=4096.
// Single-barrier ping-pong: LDS halves As/Bs[2]; loop-top __syncthreads
// drains staging of tile kt (issued last iteration, latency hidden under
// MFMA); tile kt+1 staging issued before this tile's MFMA cluster.
// j-remap: wave's n-columns = wn2 + (j&1)*16 + (j>>1)*64 + l16 so acc[i][j]
// and acc[i][j+2] hold the RoPE pair (d, d+64) in-register.
// MODE 0: C fp32 row-major [M][N] (O-projection -> d_out)
// MODE 1: Q head-major bf16 [b][32][s][128], RoPE+scale fused
// MODE 4 (AF32): fused KV; n0<1024 -> K bf16 [b][8][s][128] with RoPE;
//                n0>=1024 -> V^T bf16 [b][8][128][s]
// ---------------------------------------------------------------------------
template <int MODE, bool AF32>
__global__ __launch_bounds__(256, 2)
void gemm_bt(const float* __restrict__ Af, const float* __restrict__ A2f,
             const ushort* __restrict__ Abf, const ushort* __restrict__ Bt,
             ushort* __restrict__ C, ushort* __restrict__ C2,
             float* __restrict__ Cf, const int* __restrict__ posp,
             int N, float scale) {
  constexpr int K = 4096;
  __shared__ alignas(16) ushort As[2][128 * 32];
  __shared__ alignas(16) ushort Bs[2][128 * 32];
  const int tid = threadIdx.x;
  const int wave = tid >> 6, lane = tid & 63;
  const int quad = lane >> 4, l16 = lane & 15;
  const int m0 = blockIdx.y * 128, n0 = blockIdx.x * 128;
  const int wm = (wave & 1) * 64, wn2 = (wave >> 1) * 32;

  const size_t aoff = (size_t)(m0 + wave * 16 + (lane >> 2)) * K + (lane & 3) * 8;
  const float* gAf = nullptr;
  const ushort* gAb = nullptr;
  if constexpr (AF32) {
    const float* Ause = Af;
    if constexpr (MODE == 4) {
      if (n0 >= 1024) Ause = A2f;  // V half reads `value`
    }
    gAf = Ause + aoff;
  } else {
    gAb = Abf + aoff;
  }
  const ushort* gB = Bt + (size_t)(n0 + wave * 16 + (lane >> 2)) * K + (lane & 3) * 8;
  const int woff = wave * 512;  // wave-uniform LDS sub-base
  constexpr size_t rstep = (size_t)64 * K;

  f32x4 acc[4][4] = {};

  // ---- prologue: stage tile 0 into half 0 ----
  if constexpr (AF32) {
    const float4 a0 = *(const float4*)(gAf);
    const float4 a1 = *(const float4*)(gAf + 4);
    const float4 b0 = *(const float4*)(gAf + rstep);
    const float4 b1 = *(const float4*)(gAf + rstep + 4);
    uint4v v0, v1;
    v0[0] = cvt_pk_bf16(a0.x, a0.y); v0[1] = cvt_pk_bf16(a0.z, a0.w);
    v0[2] = cvt_pk_bf16(a1.x, a1.y); v0[3] = cvt_pk_bf16(a1.z, a1.w);
    v1[0] = cvt_pk_bf16(b0.x, b0.y); v1[1] = cvt_pk_bf16(b0.z, b0.w);
    v1[2] = cvt_pk_bf16(b1.x, b1.y); v1[3] = cvt_pk_bf16(b1.z, b1.w);
    *(uint4v*)(As[0] + woff + lane * 8) = v0;
    *(uint4v*)(As[0] + 2048 + woff + lane * 8) = v1;
  } else {
    async_copy16(gAb, As[0] + woff);
    async_copy16(gAb + rstep, As[0] + 2048 + woff);
  }
  async_copy16(gB, Bs[0] + woff);
  async_copy16(gB + rstep, Bs[0] + 2048 + woff);

  for (int kt = 0; kt < K; kt += 32) {
    const int cur = (kt >> 5) & 1;
    const int nxt = cur ^ 1;
    const bool pf = (kt + 32) < K;
    __syncthreads();  // tile kt staged & visible; prev reads of half nxt done

    // issue tile kt+1 staging (drained at next loop-top barrier)
    float4 a0, a1, b0, b1;
    if constexpr (AF32) {
      if (pf) {  // loads issued now; cvt+ds_write sunk below the MFMAs
        a0 = *(const float4*)(gAf + kt + 32);
        a1 = *(const float4*)(gAf + kt + 36);
        b0 = *(const float4*)(gAf + rstep + kt + 32);
        b1 = *(const float4*)(gAf + rstep + kt + 36);
      }
    } else {
      if (pf) {
        async_copy16(gAb + kt + 32, As[nxt] + woff);
        async_copy16(gAb + rstep + kt + 32, As[nxt] + 2048 + woff);
      }
    }
    if (pf) {
      async_copy16(gB + kt + 32, Bs[nxt] + woff);
      async_copy16(gB + rstep + kt + 32, Bs[nxt] + 2048 + woff);
    }

    short8 af[4], bfrag[4];
#pragma unroll
    for (int i = 0; i < 4; i++) {
      af[i] = *(const short8*)(As[cur] + (wm + i * 16 + l16) * 32 + quad * 8);
      bfrag[i] = *(const short8*)(
          Bs[cur] + (wn2 + (i & 1) * 16 + (i >> 1) * 64 + l16) * 32 + quad * 8);
    }
    __builtin_amdgcn_s_setprio(1);
#pragma unroll
    for (int i = 0; i < 4; i++)
#pragma unroll
      for (int j = 0; j < 4; j++)
        acc[i][j] = __builtin_amdgcn_mfma_f32_16x16x32_bf16(af[i], bfrag[j],
                                                            acc[i][j], 0, 0, 0);
    __builtin_amdgcn_s_setprio(0);

    if constexpr (AF32) {
      if (pf) {  // A-load latency hidden under the MFMA cluster above
        uint4v v0, v1;
        v0[0] = cvt_pk_bf16(a0.x, a0.y); v0[1] = cvt_pk_bf16(a0.z, a0.w);
        v0[2] = cvt_pk_bf16(a1.x, a1.y); v0[3] = cvt_pk_bf16(a1.z, a1.w);
        v1[0] = cvt_pk_bf16(b0.x, b0.y); v1[1] = cvt_pk_bf16(b0.z, b0.w);
        v1[2] = cvt_pk_bf16(b1.x, b1.y); v1[3] = cvt_pk_bf16(b1.z, b1.w);
        *(uint4v*)(As[nxt] + woff + lane * 8) = v0;
        *(uint4v*)(As[nxt] + 2048 + woff + lane * 8) = v1;
      }
    }
  }

  // ---------------- epilogue ----------------
  if constexpr (MODE == 0) {
#pragma unroll
    for (int i = 0; i < 4; i++)
#pragma unroll
      for (int j = 0; j < 4; j++) {
        const int n = n0 + wn2 + (j & 1) * 16 + (j >> 1) * 64 + l16;
        const int mb = m0 + wm + i * 16 + quad * 4;
#pragma unroll
        for (int r = 0; r < 4; r++)
          Cf[(size_t)(mb + r) * N + n] = acc[i][j][r] * scale;
      }
  } else {
    const bool kv_v = (MODE == 4) && (n0 >= 1024);
    if (!kv_v) {
      // RoPE epilogue (Q: MODE 1, K: MODE 4 low half)
      const int pos0 = posp[0];
      const int h = (MODE == 1) ? (n0 >> 7) : (n0 >> 7);
      const int NH = (MODE == 1) ? 32 : 8;
      constexpr float lgbase = -0.20762050593045983f;  // -log2(10000)/64
      float invf[2];
      invf[0] = exp2f((float)(wn2 + l16) * lgbase);
      invf[1] = exp2f((float)(wn2 + 16 + l16) * lgbase);
#pragma unroll
      for (int i = 0; i < 4; i++) {
#pragma unroll
        for (int r = 0; r < 4; r++) {
          const int m = m0 + wm + i * 16 + quad * 4 + r;
          const int s = m & 1023, bb = m >> 10;
          const float p = (float)(s + pos0);
          ushort* row = C + (((size_t)bb * NH + h) * 1024 + s) * 128;
#pragma unroll
          for (int jj = 0; jj < 2; jj++) {
            float sn, cs;
            sincosf(p * invf[jj], &sn, &cs);
            const float x1 = acc[i][jj][r] * scale;
            const float x2 = acc[i][jj + 2][r] * scale;
            const int dlo = wn2 + jj * 16 + l16;
            row[dlo] = f2bf(x1 * cs - x2 * sn);
            row[dlo + 64] = f2bf(x2 * cs + x1 * sn);
          }
        }
      }
    } else {
      // V half: no RoPE, transposed write [b][8][128][s]
      const int hh = (n0 - 1024) >> 7;
#pragma unroll
      for (int i = 0; i < 4; i++)
#pragma unroll
        for (int j = 0; j < 4; j++) {
          const int d = wn2 + (j & 1) * 16 + (j >> 1) * 64 + l16;
          const int mb = m0 + wm + i * 16 + quad * 4;
#pragma unroll
          for (int r = 0; r < 4; r++) {
            const int m = mb + r;
            const int bb = m >> 10, s = m & 1023;
            C2[(((size_t)bb * 8 + hh) * 128 + d) * 1024 + s] = f2bf(acc[i][j][r]);
          }
        }
    }
  }
}

// ---------------------------------------------------------------------------
// Flash attention (unchanged from R7).
// Block = 64 q-rows (4 waves x 16), 16 k-tiles of 64. One barrier per k-tile:
//   top barrier (drains prev-issued staging) -> mask reg loads -> QK MFMA
//   -> issue K/V staging for kt+64 into ping-pong buffers -> softmax
//   (defer-max, deferred-l) -> P to swizzled LDS via cvt_pk -> PV MFMA.
// XCD-chunked block swizzle keeps the 64 blocks sharing a (b,hkv) K/V panel
// on one XCD's L2. LDS 72 KB -> 2 blocks/CU.
// ---------------------------------------------------------------------------
__global__ __launch_bounds__(256, 2)
void attn_kernel(const ushort* __restrict__ Qh, const ushort* __restrict__ Kh,
                 const ushort* __restrict__ Vt, const ushort* __restrict__ Mk,
                 ushort* __restrict__ Oh) {
  __shared__ alignas(16) ushort smem[36864];  // 72 KB
  ushort* const Ks0 = smem;
  ushort* const Ks1 = smem + 8192;
  ushort* const Vs0 = smem + 16384;
  ushort* const Vs1 = smem + 24576;
  ushort* const Ps = smem + 32768;   // 4 waves x 16x64 = 4096 ushorts (8 KB)
  ushort* const Qtmp = smem + 16384;  // overlays Vs0 (8192 ushorts), pre-loop only

  // XCD-chunked swizzle (bijective: 2048 = 8 * 256)
  int bid = (blockIdx.z * 32 + blockIdx.y) * 16 + blockIdx.x;
  bid = (bid & 7) * 256 + (bid >> 3);
  const int b = bid >> 9, h = (bid >> 4) & 31;
  const int q0 = (bid & 15) * 64;
  const int hkv = h >> 2;
  const int tid = threadIdx.x;
  const int wave = tid >> 6, lane = tid & 63;
  const int quad = lane >> 4, l16 = lane & 15;
  const int vr = lane >> 3;
  const int vkc = (lane & 7) ^ (vr & 7);

  const ushort* Qg = Qh + (((size_t)b * 32 + h) * 1024 + q0) * 128;
  const ushort* Kg = Kh + ((size_t)b * 8 + hkv) * (size_t)(1024 * 128);
  const ushort* Vg = Vt + ((size_t)b * 8 + hkv) * (size_t)(128 * 1024);
  const ushort* Mg = Mk + ((size_t)b * 1024 + q0) * 1024;

  // ---- prologue: stage Q (64x128) + K(0); hoist Q to registers ----
#pragma unroll
  for (int c = 0; c < 4; c++) {  // Q, swizzled: chunk j of row r at slot j^(r&15)
    const int i = wave * 4 + c;
    const int row = i * 4 + quad;
    const int kc = l16 ^ (c * 4 + quad);  // c*4+quad == row&15
    async_copy16(Qg + (size_t)row * 128 + kc * 8, Qtmp + i * 512);
  }
#pragma unroll
  for (int c = 0; c < 4; c++) {  // K(0) 64x128 -> Ks0, same swizzle
    const int i = wave * 4 + c;
    const int row = i * 4 + quad;
    const int kc = l16 ^ (c * 4 + quad);
    async_copy16(Kg + (size_t)row * 128 + kc * 8, Ks0 + i * 512);
  }
  __asm__ volatile("s_waitcnt vmcnt(0)" ::: "memory");  // own Q rows landed
  short8 qreg[4];
#pragma unroll
  for (int ks = 0; ks < 4; ks++)
    qreg[ks] = *(const short8*)(Qtmp + (size_t)(wave * 16 + l16) * 128 +
                                (((ks * 4 + quad) ^ l16) * 8));
  __syncthreads();  // all waves done with Qtmp before V0 staging overwrites it
#pragma unroll
  for (int c = 0; c < 4; c++) {  // V(0) 128x64 (V^T layout) -> Vs0
    const int i = wave * 4 + c;
    async_copy16(Vg + (size_t)(i * 8 + vr) * 1024 + vkc * 8, Vs0 + i * 512);
  }

  float m_i[4], l_p[4];
#pragma unroll
  for (int r = 0; r < 4; r++) { m_i[r] = -1e30f; l_p[r] = 0.0f; }
  f32x4 acc[8] = {};

  ushort* const PW = Ps + wave * 1024;  // 16 rows x 64 cols bf16, XOR-swizzled

  for (int kt = 0; kt < 1024; kt += 64) {
    const int it = kt >> 6;
    ushort* const Kc = (it & 1) ? Ks1 : Ks0;
    ushort* const Vc = (it & 1) ? Vs1 : Vs0;
    ushort* const Kn = (it & 1) ? Ks0 : Ks1;
    ushort* const Vn = (it & 1) ? Vs0 : Vs1;
    __syncthreads();  // single barrier: staged tile kt now visible everywhere

    // mask loads for this tile -> registers (consumed after QK; latency hidden)
    ushort mr[4][4];
#pragma unroll
    for (int nt = 0; nt < 4; nt++)
#pragma unroll
      for (int r = 0; r < 4; r++)
        mr[nt][r] = Mg[(size_t)(wave * 16 + quad * 4 + r) * 1024 +
                       kt + nt * 16 + l16];

    // S = Q K^T
    f32x4 s[4] = {};
    __builtin_amdgcn_s_setprio(1);
#pragma unroll
    for (int ks = 0; ks < 4; ks++) {
      const int ko = ((ks * 4 + quad) ^ l16) * 8;
#pragma unroll
      for (int nt = 0; nt < 4; nt++) {
        const short8 bk = *(const short8*)(Kc + (size_t)(nt * 16 + l16) * 128 + ko);
        s[nt] = __builtin_amdgcn_mfma_f32_16x16x32_bf16(qreg[ks], bk, s[nt], 0, 0, 0);
      }
    }
    __builtin_amdgcn_s_setprio(0);

    // issue next tile's staging into the ping-pong buffers (drained at next
    // loop-top barrier; overlaps softmax+PV below)
    if (kt < 960) {
#pragma unroll
      for (int c = 0; c < 4; c++) {
        const int i = wave * 4 + c;
        const int row = i * 4 + quad;
        const int kc = l16 ^ (c * 4 + quad);
        async_copy16(Kg + (size_t)(kt + 64 + row) * 128 + kc * 8, Kn + i * 512);
      }
#pragma unroll
      for (int c = 0; c < 4; c++) {
        const int i = wave * 4 + c;
        async_copy16(Vg + (size_t)(i * 8 + vr) * 1024 + kt + 64 + vkc * 8, Vn + i * 512);
      }
    }

    // additive mask (C layout: row = quad*4+r, col = l16)
#pragma unroll
    for (int nt = 0; nt < 4; nt++)
#pragma unroll
      for (int r = 0; r < 4; r++) s[nt][r] += bf2f(mr[nt][r]);

    // row max (16-lane reduce) + defer-max vote
    float mx[4];
    int need = 0;
#pragma unroll
    for (int r = 0; r < 4; r++) {
      float v = fmaxf(fmaxf(s[0][r], s[1][r]), fmaxf(s[2][r], s[3][r]));
#pragma unroll
      for (int off = 1; off < 16; off <<= 1) v = fmaxf(v, __shfl_xor(v, off));
      mx[r] = v;
      need |= (v > m_i[r] + 8.0f) ? 1 : 0;
    }
    if (__any(need)) {  // rescale path (rare after warm-up: defer-max THR=8)
#pragma unroll
      for (int r = 0; r < 4; r++) {
        const float mnew = fmaxf(m_i[r], mx[r]);
        const float al = __expf(m_i[r] - mnew);
        m_i[r] = mnew;
        l_p[r] *= al;
#pragma unroll
        for (int dt = 0; dt < 8; dt++) acc[dt][r] *= al;
      }
    }

    // exp (bounded by e^8 under defer) + per-lane partial row sums + P -> LDS.
    // P->bf16 via v_cvt_pk_bf16_f32 (RNE, 1 inst per 2 vals). P element
    // (row,col) at row*64 + (col ^ (((row>>1)&7)*8)): conflict-free (measured
    // 0 in R4/R6) for quad-row u16 writes and b128 A-fragment reads.
#pragma unroll
    for (int r = 0; r < 4; r++) {
      const int prow = quad * 4 + r;
      const int key8 = ((prow >> 1) & 7) * 8;
      const float p0 = __expf(s[0][r] - m_i[r]);
      const float p1 = __expf(s[1][r] - m_i[r]);
      const float p2 = __expf(s[2][r] - m_i[r]);
      const float p3 = __expf(s[3][r] - m_i[r]);
      l_p[r] += (p0 + p1) + (p2 + p3);
      const unsigned int u01 = cvt_pk_bf16(p0, p1);
      const unsigned int u23 = cvt_pk_bf16(p2, p3);
      ushort* row = PW + prow * 64;
      row[l16 ^ key8] = (ushort)u01;
      row[(16 + l16) ^ key8] = (ushort)(u01 >> 16);
      row[(32 + l16) ^ key8] = (ushort)u23;
      row[(48 + l16) ^ key8] = (ushort)(u23 >> 16);
    }
    __asm__ volatile("s_waitcnt lgkmcnt(0)" ::: "memory");

    // O += P V (A: P[m=l16][k], B: V^T[d][k])
    __builtin_amdgcn_s_setprio(1);
#pragma unroll
    for (int kk = 0; kk < 2; kk++) {
      const int pslot = ((kk * 4 + quad) ^ (l16 >> 1)) * 8;  // key = (row>>1)&7
      const short8 ap = *(const short8*)(PW + (size_t)l16 * 64 + pslot);
#pragma unroll
      for (int dt = 0; dt < 8; dt++) {
        const int vo = ((kk * 4 + quad) ^ (l16 & 7)) * 8;
        const short8 bv = *(const short8*)(Vc + (size_t)(dt * 16 + l16) * 64 + vo);
        acc[dt] = __builtin_amdgcn_mfma_f32_16x16x32_bf16(ap, bv, acc[dt], 0, 0, 0);
      }
    }
    __builtin_amdgcn_s_setprio(0);
  }

  // epilogue: finish deferred l reduce, normalize, store Oh[b*1024+s][h*128+d]
  ushort* Og = Oh + ((size_t)b * 1024 + q0 + wave * 16) * 4096 + h * 128;
#pragma unroll
  for (int r = 0; r < 4; r++) {
    float l = l_p[r];
#pragma unroll
    for (int off = 1; off < 16; off <<= 1) l += __shfl_xor(l, off);
    const float inv = 1.0f / l;
#pragma unroll
    for (int dt = 0; dt < 8; dt++)
      Og[(size_t)(quad * 4 + r) * 4096 + dt * 16 + l16] = f2bf(acc[dt][r] * inv);
  }
}

// ---------------------------------------------------------------------------
extern "C" void kernel_launch(void* const* d_in, const int* in_sizes, int n_in,
                              void* d_out, int out_size, void* d_ws, size_t ws_size,
                              hipStream_t stream) {
  (void)in_sizes; (void)n_in; (void)out_size; (void)ws_size;
  const float* query = (const float*)d_in[0];
  const float* key = (const float*)d_in[1];
  const float* value = (const float*)d_in[2];
  const float* mask = (const float*)d_in[3];
  const float* wq = (const float*)d_in[4];
  const float* wk = (const float*)d_in[5];
  const float* wv = (const float*)d_in[6];
  const float* wo = (const float*)d_in[7];
  const int* pos = (const int*)d_in[8];
  float* out = (float*)d_out;

  char* ws = (char*)d_ws;
  const size_t MB = 1024 * 1024;
  // Region reuse plan (peak 104 MiB):
  ushort* qb = (ushort*)(ws + 0 * MB);     // [0,32): qb -> Khb[0,8)+Vtb[8,16)
  ushort* Khb = (ushort*)(ws + 0 * MB);
  ushort* Vtb = (ushort*)(ws + 8 * MB);
  ushort* wqT = (ushort*)(ws + 32 * MB);   // [32,64): wqT -> wkvT[32,48) -> Ohb[32,64)
  ushort* wkvT = (ushort*)(ws + 32 * MB);
  ushort* Ohb = (ushort*)(ws + 32 * MB);
  ushort* Qhb = (ushort*)(ws + 64 * MB);   // [64,96): Qhb -> woT
  ushort* woT = (ushort*)(ws + 64 * MB);
  ushort* mbf = (ushort*)(ws + 96 * MB);   // [96,104)

  dim3 blk(256);
  cvt_f32_bf16<<<dim3(4096), blk, 0, stream>>>(mask, mbf, 1048576);
  cvt_f32_bf16<<<dim3(16384), blk, 0, stream>>>(query, qb, 4194304);

  transpose_cvt<<<dim3(64, 64), blk, 0, stream>>>(wq, wqT, 4096);
  // Q projection, scale + RoPE fused
  gemm_bt<1, false><<<dim3(32, 32), blk, 0, stream>>>(
      nullptr, nullptr, qb, wqT, Qhb, nullptr, nullptr, pos, 4096,
      0.08838834764831845f);

  transpose_cvt<<<dim3(16, 64), blk, 0, stream>>>(wk, wkvT, 1024);
  transpose_cvt<<<dim3(16, 64), blk, 0, stream>>>(wv, wkvT + (size_t)1024 * 4096, 1024);
  // fused K+V projection (K gets RoPE; V written transposed)
  gemm_bt<4, true><<<dim3(16, 32), blk, 0, stream>>>(
      key, value, nullptr, wkvT, Khb, Vtb, nullptr, pos, 2048, 1.0f);

  attn_kernel<<<dim3(16, 32, 4), blk, 0, stream>>>(Qhb, Khb, Vtb, mbf, Ohb);

  transpose_cvt<<<dim3(64, 64), blk, 0, stream>>>(wo, woT, 4096);  // Qhb dead
  // output projection -> fp32 d_out
  gemm_bt<0, false><<<dim3(32, 32), blk, 0, stream>>>(
      nullptr, nullptr, Ohb, woT, nullptr, nullptr, out, pos, 4096, 1.0f);
}

// Round 6
// 919.588 us; speedup vs baseline: 1.2965x; 1.0142x over previous
//
#include <hip/hip_runtime.h>

// GQA attention forward. Inputs/outputs FP32 (per reference); internal compute
// bf16 MFMA. BS=4 SEQ=1024 DM=4096 HQ=32 HKV=8 D_K=DV=128.
// R9: Q-proj and O-proj moved to gemm256: 256^2 tile, BK=64, 8 waves (512
// thr), 128 KB LDS double-buffer, 4 phases/K-tile (C-quadrant Gray order),
// counted vmcnt(2)/vmcnt(4) (never 0 in steady state), slot^(row&7) LDS
// swizzle (conflict-free b128), setprio around MFMA clusters. All stages go
// to the non-active buffer; every hazard barrier-separated (analysis in
// comments). KV GEMM (fp32-input) keeps the R8 128^2 ping-pong; attn = R7.

using ushort = unsigned short;
typedef __attribute__((ext_vector_type(8))) short short8;   // 8 bf16 (4 VGPRs)
typedef __attribute__((ext_vector_type(4))) short short4v;  // 4 bf16
typedef __attribute__((ext_vector_type(4))) float f32x4;    // MFMA C/D
typedef __attribute__((ext_vector_type(4))) unsigned int uint4v;

__device__ __forceinline__ ushort f2bf(float x) {  // RNE fp32->bf16
  unsigned int u = __float_as_uint(x);
  u += 0x7FFFu + ((u >> 16) & 1u);
  return (ushort)(u >> 16);
}
__device__ __forceinline__ float bf2f(ushort h) {
  return __uint_as_float(((unsigned int)h) << 16);
}
// RNE pack: lo -> bits[15:0], hi -> bits[31:16] (T12; no builtin on gfx950)
__device__ __forceinline__ unsigned int cvt_pk_bf16(float lo, float hi) {
  unsigned int r;
  asm("v_cvt_pk_bf16_f32 %0, %1, %2" : "=v"(r) : "v"(lo), "v"(hi));
  return r;
}

__device__ __forceinline__ void async_copy16(const void* g, void* l) {
  // LDS dest = wave-uniform base + lane*16 (pass uniform l).
  __builtin_amdgcn_global_load_lds((const __attribute__((address_space(1))) void*)g,
                                   (__attribute__((address_space(3))) void*)l, 16, 0, 0);
}

// ---------------------------------------------------------------------------
// fp32 -> bf16 elementwise, 4 elems/thread
// ---------------------------------------------------------------------------
__global__ __launch_bounds__(256)
void cvt_f32_bf16(const float* __restrict__ in, ushort* __restrict__ out, int n4) {
  const int i = blockIdx.x * 256 + threadIdx.x;
  if (i < n4) {
    const float4 f = ((const float4*)in)[i];
    short4v v;
    v[0] = (short)f2bf(f.x); v[1] = (short)f2bf(f.y);
    v[2] = (short)f2bf(f.z); v[3] = (short)f2bf(f.w);
    ((short4v*)out)[i] = v;
  }
}

// ---------------------------------------------------------------------------
// Weight transpose+convert: B fp32 [4096][N] -> Bt bf16 [N][4096]
// ---------------------------------------------------------------------------
__global__ __launch_bounds__(256)
void transpose_cvt(const float* __restrict__ B, ushort* __restrict__ Bt, int N) {
  __shared__ ushort t[64][72];  // +8 pad breaks bank conflicts
  const int n0 = blockIdx.x * 64, k0 = blockIdx.y * 64;
  const int tid = threadIdx.x;
  const int r = tid >> 3, c8 = (tid & 7) * 8;
#pragma unroll
  for (int p = 0; p < 2; p++) {
    const float* src = B + (size_t)(k0 + r + p * 32) * N + n0 + c8;
    const float4 f0 = *(const float4*)src;
    const float4 f1 = *(const float4*)(src + 4);
    ushort* d = &t[r + p * 32][c8];
    d[0] = f2bf(f0.x); d[1] = f2bf(f0.y); d[2] = f2bf(f0.z); d[3] = f2bf(f0.w);
    d[4] = f2bf(f1.x); d[5] = f2bf(f1.y); d[6] = f2bf(f1.z); d[7] = f2bf(f1.w);
  }
  __syncthreads();
#pragma unroll
  for (int p = 0; p < 2; p++) {
    const int n = r + p * 32;
    short8 o;
#pragma unroll
    for (int j = 0; j < 8; j++) o[j] = (short)t[c8 + j][n];
    *(short8*)(Bt + (size_t)(n0 + n) * 4096 + k0 + c8) = o;
  }
}

// ---------------------------------------------------------------------------
// gemm256: C = A[4096x4096] * Bt[Nx4096]^T, 256^2 tile, BK=64, 8 waves.
// Waves tile each 128x128 C-quadrant as 4(wr) x 2(wc): per wave per quadrant
// 2 m-frags x 4 n-frags; acc[2][2][2][4] = 128 VGPR.
// n-frag remap: col = Nq*128 + wc*32 + (g&1)*16 + (g>>1)*64 + l16, so
// (g, g+2) hold the RoPE pair (d, d+64) in-thread.
// LDS (ushort idx): buf b at b*32768; A halves at +Mq*8192; B at +16384+Nq*8192.
// Swizzle: k-chunk c of row r stored at slot c^(r&7) (16B slots) — staged by
// pre-swizzling the per-lane global source (linear LDS dest for gload_lds).
// Phases per K-tile t (buffer bo=t&1; ALL stages go to buffer bn=bo^1):
//  ph1 (Mq0,Nq0) read A-lo+B-lo | stage A-lo(t+1) | end: vmcnt(2)
//  ph2 (Mq1,Nq0) read A-hi      | stage B-lo(t+1)
//  ph3 (Mq1,Nq1) read B-hi      | stage B-hi(t+1)
//  ph4 (Mq0,Nq1) read A-lo      | stage A-hi(t+1) | end: vmcnt(4)
// vmcnt(4) @end-ph4: A-lo,B-lo(t+1) landed (allows B-hi,A-hi in flight).
// vmcnt(2) @end-ph1: A-hi,B-hi(t) landed (allows A-lo(t+1) in flight).
// Hazards: stage into bn region R vs R's last read (tile t-1): separated by
// >=1 barrier (A-lo read ph4(t-1) vs stage ph1(t); A-hi read ph2/3(t-1) vs
// ph4(t); B-lo read ph1(t-1) vs ph2(t); B-hi read ph3(t-1) vs ph3(t)).
// MODE 0: fp32 row-major out. MODE 1: Q head-major bf16 + RoPE + scale.
// ---------------------------------------------------------------------------
template <int MQ>
__device__ __forceinline__ void read_afrag(const ushort* Ab, int arbase,
                                           const int (&kslot)[2], short8 (&af)[2][2]) {
#pragma unroll
  for (int f = 0; f < 2; f++)
#pragma unroll
    for (int kk = 0; kk < 2; kk++)
      af[f][kk] = *(const short8*)(Ab + MQ * 8192 + arbase + f * 1024 + kslot[kk]);
}
template <int NQ>
__device__ __forceinline__ void read_bfrag(const ushort* Bb, int brbase,
                                           const int (&kslot)[2], short8 (&bg)[4][2]) {
#pragma unroll
  for (int g = 0; g < 4; g++)
#pragma unroll
    for (int kk = 0; kk < 2; kk++)
      bg[g][kk] = *(const short8*)(Bb + NQ * 8192 + brbase + (g & 1) * 1024 +
                                   (g >> 1) * 4096 + kslot[kk]);
}
__device__ __forceinline__ void mma_quad(short8 (&af)[2][2], short8 (&bg)[4][2],
                                         f32x4 (&q)[2][4]) {
#pragma unroll
  for (int f = 0; f < 2; f++)
#pragma unroll
    for (int g = 0; g < 4; g++)
#pragma unroll
      for (int kk = 0; kk < 2; kk++)
        q[f][g] = __builtin_amdgcn_mfma_f32_16x16x32_bf16(af[f][kk], bg[g][kk],
                                                          q[f][g], 0, 0, 0);
}

template <int MODE>
__global__ __launch_bounds__(512, 2)
void gemm256(const ushort* __restrict__ A, const ushort* __restrict__ Bt,
             ushort* __restrict__ C, float* __restrict__ Cf,
             const int* __restrict__ posp, int N, float scale) {
  constexpr int K = 4096, NT = 64;
  __shared__ alignas(16) ushort lds[65536];  // 128 KB
  const int tid = threadIdx.x;
  const int wave = tid >> 6, lane = tid & 63;
  const int quad = lane >> 4, l16 = lane & 15;
  const int wr = wave & 3, wc = wave >> 2;
  const int m0 = blockIdx.y * 256, n0 = blockIdx.x * 256;

  // staging: thread covers row srow (of 64) x slot tid&7; global chunk
  // pre-swizzled so LDS linear slot s holds chunk s^(row&7).
  const int srow = tid >> 3, schunk = (tid & 7) ^ ((tid >> 3) & 7);
  const ushort* gA = A + (size_t)(m0 + srow) * K + schunk * 8;
  const ushort* gB = Bt + (size_t)(n0 + srow) * K + schunk * 8;
  ushort* const stbase = lds + wave * 512;  // HW adds lane*16B

  const int sw = l16 & 7;
  const int kslot[2] = {(quad ^ sw) * 8, ((4 + quad) ^ sw) * 8};
  const int arbase = (wr * 32 + l16) * 64;
  const int brbase = (wc * 32 + l16) * 64;

  short8 af[2][2], bg[4][2];
  f32x4 acc[2][2][2][4] = {};

  auto STAGE = [&](int bufo, int isB, int half, int t) {
    const ushort* src = (isB ? gB : gA) + (size_t)(half * 128) * K + t * 64;
    ushort* dst = stbase + bufo + isB * 16384 + half * 8192;
    async_copy16(src, dst);                          // rows 0-63 of half
    async_copy16(src + (size_t)64 * K, dst + 4096);  // rows 64-127
  };

  // prologue: tile 0, issue order A-lo, B-lo, B-hi, A-hi (matches steady state)
  STAGE(0, 0, 0, 0);
  STAGE(0, 1, 0, 0);
  STAGE(0, 1, 1, 0);
  STAGE(0, 0, 1, 0);
  __asm__ volatile("s_waitcnt vmcnt(4)" ::: "memory");  // A-lo,B-lo landed
  __builtin_amdgcn_s_barrier();

  for (int t = 0; t < NT; ++t) {
    const int bo = (t & 1) << 15;
    const int bn = bo ^ 32768;
    const bool pf = (t + 1) < NT;
    const ushort* Ab = lds + bo;
    const ushort* Bb = lds + bo + 16384;

    // ---- phase 1: (Mq0,Nq0) ----
    read_afrag<0>(Ab, arbase, kslot, af);
    read_bfrag<0>(Bb, brbase, kslot, bg);
    if (pf) STAGE(bn, 0, 0, t + 1);  // A-lo(t+1)
    __asm__ volatile("s_waitcnt lgkmcnt(8)" ::: "memory");
    __builtin_amdgcn_s_barrier();
    __asm__ volatile("s_waitcnt lgkmcnt(0)" ::: "memory");
    __builtin_amdgcn_sched_barrier(0);
    __builtin_amdgcn_s_setprio(1);
    mma_quad(af, bg, acc[0][0]);
    __builtin_amdgcn_s_setprio(0);
    if (pf) {
      __asm__ volatile("s_waitcnt vmcnt(2)" ::: "memory");  // A-hi,B-hi(t) in
    } else {
      __asm__ volatile("s_waitcnt vmcnt(0)" ::: "memory");
    }
    __builtin_amdgcn_s_barrier();

    // ---- phase 2: (Mq1,Nq0), reuse bg ----
    read_afrag<1>(Ab, arbase, kslot, af);
    if (pf) STAGE(bn, 1, 0, t + 1);  // B-lo(t+1)
    __builtin_amdgcn_s_barrier();
    __asm__ volatile("s_waitcnt lgkmcnt(0)" ::: "memory");
    __builtin_amdgcn_sched_barrier(0);
    __builtin_amdgcn_s_setprio(1);
    mma_quad(af, bg, acc[1][0]);
    __builtin_amdgcn_s_setprio(0);
    __builtin_amdgcn_s_barrier();

    // ---- phase 3: (Mq1,Nq1), reuse af ----
    read_bfrag<1>(Bb, brbase, kslot, bg);
    if (pf) STAGE(bn, 1, 1, t + 1);  // B-hi(t+1)
    __builtin_amdgcn_s_barrier();
    __asm__ volatile("s_waitcnt lgkmcnt(0)" ::: "memory");
    __builtin_amdgcn_sched_barrier(0);
    __builtin_amdgcn_s_setprio(1);
    mma_quad(af, bg, acc[1][1]);
    __builtin_amdgcn_s_setprio(0);
    __builtin_amdgcn_s_barrier();

    // ---- phase 4: (Mq0,Nq1), re-read A-lo, reuse bg ----
    read_afrag<0>(Ab, arbase, kslot, af);
    if (pf) STAGE(bn, 0, 1, t + 1);  // A-hi(t+1)
    __builtin_amdgcn_s_barrier();
    __asm__ volatile("s_waitcnt lgkmcnt(0)" ::: "memory");
    __builtin_amdgcn_sched_barrier(0);
    __builtin_amdgcn_s_setprio(1);
    mma_quad(af, bg, acc[0][1]);
    __builtin_amdgcn_s_setprio(0);
    if (pf) {
      __asm__ volatile("s_waitcnt vmcnt(4)" ::: "memory");  // A-lo,B-lo(t+1) in
    }
    __builtin_amdgcn_s_barrier();
  }

  // ---------------- epilogue ----------------
  if constexpr (MODE == 0) {
#pragma unroll
    for (int Mq = 0; Mq < 2; Mq++)
#pragma unroll
      for (int Nq = 0; Nq < 2; Nq++)
#pragma unroll
        for (int f = 0; f < 2; f++)
#pragma unroll
          for (int g = 0; g < 4; g++) {
            const int m = m0 + Mq * 128 + wr * 32 + f * 16 + quad * 4;
            const int n = n0 + Nq * 128 + wc * 32 + (g & 1) * 16 +
                          (g >> 1) * 64 + l16;
#pragma unroll
            for (int rr = 0; rr < 4; rr++)
              Cf[(size_t)(m + rr) * N + n] = acc[Mq][Nq][f][g][rr] * scale;
          }
  } else {
    // RoPE epilogue: head h = blockIdx.x*2 + Nq, d = wc*32+(g&1)*16+(g>>1)*64+l16
    const int pos0 = posp[0];
    constexpr float lgbase = -0.20762050593045983f;  // -log2(10000)/64
    float invf[2];
    invf[0] = exp2f((float)(wc * 32 + l16) * lgbase);
    invf[1] = exp2f((float)(wc * 32 + 16 + l16) * lgbase);
#pragma unroll
    for (int Mq = 0; Mq < 2; Mq++)
#pragma unroll
      for (int f = 0; f < 2; f++)
#pragma unroll
        for (int rr = 0; rr < 4; rr++) {
          const int m = m0 + Mq * 128 + wr * 32 + f * 16 + quad * 4 + rr;
          const int s = m & 1023, bb = m >> 10;
          const float p = (float)(s + pos0);
#pragma unroll
          for (int Nq = 0; Nq < 2; Nq++) {
            const int h = blockIdx.x * 2 + Nq;
            ushort* row = C + (((size_t)bb * 32 + h) * 1024 + s) * 128;
#pragma unroll
            for (int g = 0; g < 2; g++) {
              float sn, cs;
              sincosf(p * invf[g], &sn, &cs);
              const float x1 = acc[Mq][Nq][f][g][rr] * scale;
              const float x2 = acc[Mq][Nq][f][g + 2][rr] * scale;
              const int dlo = wc * 32 + g * 16 + l16;
              row[dlo] = f2bf(x1 * cs - x2 * sn);
              row[dlo + 64] = f2bf(x2 * cs + x1 * sn);
            }
          }
        }
  }
}

// ---------------------------------------------------------------------------
// gemm_bt (R8 ping-pong) — now used only for the fused KV projection.
// MODE 4 (AF32): fused KV; n0<1024 -> K bf16 [b][8][s][128] with RoPE;
//                n0>=1024 -> V^T bf16 [b][8][128][s]
// ---------------------------------------------------------------------------
template <int MODE, bool AF32>
__global__ __launch_bounds__(256, 2)
void gemm_bt(const float* __restrict__ Af, const float* __restrict__ A2f,
             const ushort* __restrict__ Abf, const ushort* __restrict__ Bt,
             ushort* __restrict__ C, ushort* __restrict__ C2,
             float* __restrict__ Cf, const int* __restrict__ posp,
             int N, float scale) {
  constexpr int K = 4096;
  __shared__ alignas(16) ushort As[2][128 * 32];
  __shared__ alignas(16) ushort Bs[2][128 * 32];
  const int tid = threadIdx.x;
  const int wave = tid >> 6, lane = tid & 63;
  const int quad = lane >> 4, l16 = lane & 15;
  const int m0 = blockIdx.y * 128, n0 = blockIdx.x * 128;
  const int wm = (wave & 1) * 64, wn2 = (wave >> 1) * 32;

  const size_t aoff = (size_t)(m0 + wave * 16 + (lane >> 2)) * K + (lane & 3) * 8;
  const float* gAf = nullptr;
  const ushort* gAb = nullptr;
  if constexpr (AF32) {
    const float* Ause = Af;
    if constexpr (MODE == 4) {
      if (n0 >= 1024) Ause = A2f;  // V half reads `value`
    }
    gAf = Ause + aoff;
  } else {
    gAb = Abf + aoff;
  }
  const ushort* gB = Bt + (size_t)(n0 + wave * 16 + (lane >> 2)) * K + (lane & 3) * 8;
  const int woff = wave * 512;  // wave-uniform LDS sub-base
  constexpr size_t rstep = (size_t)64 * K;

  f32x4 acc[4][4] = {};

  // ---- prologue: stage tile 0 into half 0 ----
  if constexpr (AF32) {
    const float4 a0 = *(const float4*)(gAf);
    const float4 a1 = *(const float4*)(gAf + 4);
    const float4 b0 = *(const float4*)(gAf + rstep);
    const float4 b1 = *(const float4*)(gAf + rstep + 4);
    uint4v v0, v1;
    v0[0] = cvt_pk_bf16(a0.x, a0.y); v0[1] = cvt_pk_bf16(a0.z, a0.w);
    v0[2] = cvt_pk_bf16(a1.x, a1.y); v0[3] = cvt_pk_bf16(a1.z, a1.w);
    v1[0] = cvt_pk_bf16(b0.x, b0.y); v1[1] = cvt_pk_bf16(b0.z, b0.w);
    v1[2] = cvt_pk_bf16(b1.x, b1.y); v1[3] = cvt_pk_bf16(b1.z, b1.w);
    *(uint4v*)(As[0] + woff + lane * 8) = v0;
    *(uint4v*)(As[0] + 2048 + woff + lane * 8) = v1;
  } else {
    async_copy16(gAb, As[0] + woff);
    async_copy16(gAb + rstep, As[0] + 2048 + woff);
  }
  async_copy16(gB, Bs[0] + woff);
  async_copy16(gB + rstep, Bs[0] + 2048 + woff);

  for (int kt = 0; kt < K; kt += 32) {
    const int cur = (kt >> 5) & 1;
    const int nxt = cur ^ 1;
    const bool pf = (kt + 32) < K;
    __syncthreads();  // tile kt staged & visible; prev reads of half nxt done

    // issue tile kt+1 staging (drained at next loop-top barrier)
    float4 a0, a1, b0, b1;
    if constexpr (AF32) {
      if (pf) {  // loads issued now; cvt+ds_write sunk below the MFMAs
        a0 = *(const float4*)(gAf + kt + 32);
        a1 = *(const float4*)(gAf + kt + 36);
        b0 = *(const float4*)(gAf + rstep + kt + 32);
        b1 = *(const float4*)(gAf + rstep + kt + 36);
      }
    } else {
      if (pf) {
        async_copy16(gAb + kt + 32, As[nxt] + woff);
        async_copy16(gAb + rstep + kt + 32, As[nxt] + 2048 + woff);
      }
    }
    if (pf) {
      async_copy16(gB + kt + 32, Bs[nxt] + woff);
      async_copy16(gB + rstep + kt + 32, Bs[nxt] + 2048 + woff);
    }

    short8 af[4], bfrag[4];
#pragma unroll
    for (int i = 0; i < 4; i++) {
      af[i] = *(const short8*)(As[cur] + (wm + i * 16 + l16) * 32 + quad * 8);
      bfrag[i] = *(const short8*)(
          Bs[cur] + (wn2 + (i & 1) * 16 + (i >> 1) * 64 + l16) * 32 + quad * 8);
    }
    __builtin_amdgcn_s_setprio(1);
#pragma unroll
    for (int i = 0; i < 4; i++)
#pragma unroll
      for (int j = 0; j < 4; j++)
        acc[i][j] = __builtin_amdgcn_mfma_f32_16x16x32_bf16(af[i], bfrag[j],
                                                            acc[i][j], 0, 0, 0);
    __builtin_amdgcn_s_setprio(0);

    if constexpr (AF32) {
      if (pf) {  // A-load latency hidden under the MFMA cluster above
        uint4v v0, v1;
        v0[0] = cvt_pk_bf16(a0.x, a0.y); v0[1] = cvt_pk_bf16(a0.z, a0.w);
        v0[2] = cvt_pk_bf16(a1.x, a1.y); v0[3] = cvt_pk_bf16(a1.z, a1.w);
        v1[0] = cvt_pk_bf16(b0.x, b0.y); v1[1] = cvt_pk_bf16(b0.z, b0.w);
        v1[2] = cvt_pk_bf16(b1.x, b1.y); v1[3] = cvt_pk_bf16(b1.z, b1.w);
        *(uint4v*)(As[nxt] + woff + lane * 8) = v0;
        *(uint4v*)(As[nxt] + 2048 + woff + lane * 8) = v1;
      }
    }
  }

  // ---------------- epilogue ----------------
  if constexpr (MODE == 0) {
#pragma unroll
    for (int i = 0; i < 4; i++)
#pragma unroll
      for (int j = 0; j < 4; j++) {
        const int n = n0 + wn2 + (j & 1) * 16 + (j >> 1) * 64 + l16;
        const int mb = m0 + wm + i * 16 + quad * 4;
#pragma unroll
        for (int r = 0; r < 4; r++)
          Cf[(size_t)(mb + r) * N + n] = acc[i][j][r] * scale;
      }
  } else {
    const bool kv_v = (MODE == 4) && (n0 >= 1024);
    if (!kv_v) {
      // RoPE epilogue (K: MODE 4 low half)
      const int pos0 = posp[0];
      const int h = n0 >> 7;
      const int NH = (MODE == 1) ? 32 : 8;
      constexpr float lgbase = -0.20762050593045983f;  // -log2(10000)/64
      float invf[2];
      invf[0] = exp2f((float)(wn2 + l16) * lgbase);
      invf[1] = exp2f((float)(wn2 + 16 + l16) * lgbase);
#pragma unroll
      for (int i = 0; i < 4; i++) {
#pragma unroll
        for (int r = 0; r < 4; r++) {
          const int m = m0 + wm + i * 16 + quad * 4 + r;
          const int s = m & 1023, bb = m >> 10;
          const float p = (float)(s + pos0);
          ushort* row = C + (((size_t)bb * NH + h) * 1024 + s) * 128;
#pragma unroll
          for (int jj = 0; jj < 2; jj++) {
            float sn, cs;
            sincosf(p * invf[jj], &sn, &cs);
            const float x1 = acc[i][jj][r] * scale;
            const float x2 = acc[i][jj + 2][r] * scale;
            const int dlo = wn2 + jj * 16 + l16;
            row[dlo] = f2bf(x1 * cs - x2 * sn);
            row[dlo + 64] = f2bf(x2 * cs + x1 * sn);
          }
        }
      }
    } else {
      // V half: no RoPE, transposed write [b][8][128][s]
      const int hh = (n0 - 1024) >> 7;
#pragma unroll
      for (int i = 0; i < 4; i++)
#pragma unroll
        for (int j = 0; j < 4; j++) {
          const int d = wn2 + (j & 1) * 16 + (j >> 1) * 64 + l16;
          const int mb = m0 + wm + i * 16 + quad * 4;
#pragma unroll
          for (int r = 0; r < 4; r++) {
            const int m = mb + r;
            const int bb = m >> 10, s = m & 1023;
            C2[(((size_t)bb * 8 + hh) * 128 + d) * 1024 + s] = f2bf(acc[i][j][r]);
          }
        }
    }
  }
}

// ---------------------------------------------------------------------------
// Flash attention (unchanged from R7).
// ---------------------------------------------------------------------------
__global__ __launch_bounds__(256, 2)
void attn_kernel(const ushort* __restrict__ Qh, const ushort* __restrict__ Kh,
                 const ushort* __restrict__ Vt, const ushort* __restrict__ Mk,
                 ushort* __restrict__ Oh) {
  __shared__ alignas(16) ushort smem[36864];  // 72 KB
  ushort* const Ks0 = smem;
  ushort* const Ks1 = smem + 8192;
  ushort* const Vs0 = smem + 16384;
  ushort* const Vs1 = smem + 24576;
  ushort* const Ps = smem + 32768;   // 4 waves x 16x64 = 4096 ushorts (8 KB)
  ushort* const Qtmp = smem + 16384;  // overlays Vs0 (8192 ushorts), pre-loop only

  // XCD-chunked swizzle (bijective: 2048 = 8 * 256)
  int bid = (blockIdx.z * 32 + blockIdx.y) * 16 + blockIdx.x;
  bid = (bid & 7) * 256 + (bid >> 3);
  const int b = bid >> 9, h = (bid >> 4) & 31;
  const int q0 = (bid & 15) * 64;
  const int hkv = h >> 2;
  const int tid = threadIdx.x;
  const int wave = tid >> 6, lane = tid & 63;
  const int quad = lane >> 4, l16 = lane & 15;
  const int vr = lane >> 3;
  const int vkc = (lane & 7) ^ (vr & 7);

  const ushort* Qg = Qh + (((size_t)b * 32 + h) * 1024 + q0) * 128;
  const ushort* Kg = Kh + ((size_t)b * 8 + hkv) * (size_t)(1024 * 128);
  const ushort* Vg = Vt + ((size_t)b * 8 + hkv) * (size_t)(128 * 1024);
  const ushort* Mg = Mk + ((size_t)b * 1024 + q0) * 1024;

  // ---- prologue: stage Q (64x128) + K(0); hoist Q to registers ----
#pragma unroll
  for (int c = 0; c < 4; c++) {  // Q, swizzled: chunk j of row r at slot j^(r&15)
    const int i = wave * 4 + c;
    const int row = i * 4 + quad;
    const int kc = l16 ^ (c * 4 + quad);  // c*4+quad == row&15
    async_copy16(Qg + (size_t)row * 128 + kc * 8, Qtmp + i * 512);
  }
#pragma unroll
  for (int c = 0; c < 4; c++) {  // K(0) 64x128 -> Ks0, same swizzle
    const int i = wave * 4 + c;
    const int row = i * 4 + quad;
    const int kc = l16 ^ (c * 4 + quad);
    async_copy16(Kg + (size_t)row * 128 + kc * 8, Ks0 + i * 512);
  }
  __asm__ volatile("s_waitcnt vmcnt(0)" ::: "memory");  // own Q rows landed
  short8 qreg[4];
#pragma unroll
  for (int ks = 0; ks < 4; ks++)
    qreg[ks] = *(const short8*)(Qtmp + (size_t)(wave * 16 + l16) * 128 +
                                (((ks * 4 + quad) ^ l16) * 8));
  __syncthreads();  // all waves done with Qtmp before V0 staging overwrites it
#pragma unroll
  for (int c = 0; c < 4; c++) {  // V(0) 128x64 (V^T layout) -> Vs0
    const int i = wave * 4 + c;
    async_copy16(Vg + (size_t)(i * 8 + vr) * 1024 + vkc * 8, Vs0 + i * 512);
  }

  float m_i[4], l_p[4];
#pragma unroll
  for (int r = 0; r < 4; r++) { m_i[r] = -1e30f; l_p[r] = 0.0f; }
  f32x4 acc[8] = {};

  ushort* const PW = Ps + wave * 1024;  // 16 rows x 64 cols bf16, XOR-swizzled

  for (int kt = 0; kt < 1024; kt += 64) {
    const int it = kt >> 6;
    ushort* const Kc = (it & 1) ? Ks1 : Ks0;
    ushort* const Vc = (it & 1) ? Vs1 : Vs0;
    ushort* const Kn = (it & 1) ? Ks0 : Ks1;
    ushort* const Vn = (it & 1) ? Vs0 : Vs1;
    __syncthreads();  // single barrier: staged tile kt now visible everywhere

    // mask loads for this tile -> registers (consumed after QK; latency hidden)
    ushort mr[4][4];
#pragma unroll
    for (int nt = 0; nt < 4; nt++)
#pragma unroll
      for (int r = 0; r < 4; r++)
        mr[nt][r] = Mg[(size_t)(wave * 16 + quad * 4 + r) * 1024 +
                       kt + nt * 16 + l16];

    // S = Q K^T
    f32x4 s[4] = {};
    __builtin_amdgcn_s_setprio(1);
#pragma unroll
    for (int ks = 0; ks < 4; ks++) {
      const int ko = ((ks * 4 + quad) ^ l16) * 8;
#pragma unroll
      for (int nt = 0; nt < 4; nt++) {
        const short8 bk = *(const short8*)(Kc + (size_t)(nt * 16 + l16) * 128 + ko);
        s[nt] = __builtin_amdgcn_mfma_f32_16x16x32_bf16(qreg[ks], bk, s[nt], 0, 0, 0);
      }
    }
    __builtin_amdgcn_s_setprio(0);

    // issue next tile's staging into the ping-pong buffers (drained at next
    // loop-top barrier; overlaps softmax+PV below)
    if (kt < 960) {
#pragma unroll
      for (int c = 0; c < 4; c++) {
        const int i = wave * 4 + c;
        const int row = i * 4 + quad;
        const int kc = l16 ^ (c * 4 + quad);
        async_copy16(Kg + (size_t)(kt + 64 + row) * 128 + kc * 8, Kn + i * 512);
      }
#pragma unroll
      for (int c = 0; c < 4; c++) {
        const int i = wave * 4 + c;
        async_copy16(Vg + (size_t)(i * 8 + vr) * 1024 + kt + 64 + vkc * 8, Vn + i * 512);
      }
    }

    // additive mask (C layout: row = quad*4+r, col = l16)
#pragma unroll
    for (int nt = 0; nt < 4; nt++)
#pragma unroll
      for (int r = 0; r < 4; r++) s[nt][r] += bf2f(mr[nt][r]);

    // row max (16-lane reduce) + defer-max vote
    float mx[4];
    int need = 0;
#pragma unroll
    for (int r = 0; r < 4; r++) {
      float v = fmaxf(fmaxf(s[0][r], s[1][r]), fmaxf(s[2][r], s[3][r]));
#pragma unroll
      for (int off = 1; off < 16; off <<= 1) v = fmaxf(v, __shfl_xor(v, off));
      mx[r] = v;
      need |= (v > m_i[r] + 8.0f) ? 1 : 0;
    }
    if (__any(need)) {  // rescale path (rare after warm-up: defer-max THR=8)
#pragma unroll
      for (int r = 0; r < 4; r++) {
        const float mnew = fmaxf(m_i[r], mx[r]);
        const float al = __expf(m_i[r] - mnew);
        m_i[r] = mnew;
        l_p[r] *= al;
#pragma unroll
        for (int dt = 0; dt < 8; dt++) acc[dt][r] *= al;
      }
    }

    // exp + per-lane partial row sums + P -> LDS via cvt_pk (conflict-free
    // swizzle, measured 0 in R4/R6).
#pragma unroll
    for (int r = 0; r < 4; r++) {
      const int prow = quad * 4 + r;
      const int key8 = ((prow >> 1) & 7) * 8;
      const float p0 = __expf(s[0][r] - m_i[r]);
      const float p1 = __expf(s[1][r] - m_i[r]);
      const float p2 = __expf(s[2][r] - m_i[r]);
      const float p3 = __expf(s[3][r] - m_i[r]);
      l_p[r] += (p0 + p1) + (p2 + p3);
      const unsigned int u01 = cvt_pk_bf16(p0, p1);
      const unsigned int u23 = cvt_pk_bf16(p2, p3);
      ushort* row = PW + prow * 64;
      row[l16 ^ key8] = (ushort)u01;
      row[(16 + l16) ^ key8] = (ushort)(u01 >> 16);
      row[(32 + l16) ^ key8] = (ushort)u23;
      row[(48 + l16) ^ key8] = (ushort)(u23 >> 16);
    }
    __asm__ volatile("s_waitcnt lgkmcnt(0)" ::: "memory");

    // O += P V (A: P[m=l16][k], B: V^T[d][k])
    __builtin_amdgcn_s_setprio(1);
#pragma unroll
    for (int kk = 0; kk < 2; kk++) {
      const int pslot = ((kk * 4 + quad) ^ (l16 >> 1)) * 8;  // key = (row>>1)&7
      const short8 ap = *(const short8*)(PW + (size_t)l16 * 64 + pslot);
#pragma unroll
      for (int dt = 0; dt < 8; dt++) {
        const int vo = ((kk * 4 + quad) ^ (l16 & 7)) * 8;
        const short8 bv = *(const short8*)(Vc + (size_t)(dt * 16 + l16) * 64 + vo);
        acc[dt] = __builtin_amdgcn_mfma_f32_16x16x32_bf16(ap, bv, acc[dt], 0, 0, 0);
      }
    }
    __builtin_amdgcn_s_setprio(0);
  }

  // epilogue: finish deferred l reduce, normalize, store Oh[b*1024+s][h*128+d]
  ushort* Og = Oh + ((size_t)b * 1024 + q0 + wave * 16) * 4096 + h * 128;
#pragma unroll
  for (int r = 0; r < 4; r++) {
    float l = l_p[r];
#pragma unroll
    for (int off = 1; off < 16; off <<= 1) l += __shfl_xor(l, off);
    const float inv = 1.0f / l;
#pragma unroll
    for (int dt = 0; dt < 8; dt++)
      Og[(size_t)(quad * 4 + r) * 4096 + dt * 16 + l16] = f2bf(acc[dt][r] * inv);
  }
}

// ---------------------------------------------------------------------------
extern "C" void kernel_launch(void* const* d_in, const int* in_sizes, int n_in,
                              void* d_out, int out_size, void* d_ws, size_t ws_size,
                              hipStream_t stream) {
  (void)in_sizes; (void)n_in; (void)out_size; (void)ws_size;
  const float* query = (const float*)d_in[0];
  const float* key = (const float*)d_in[1];
  const float* value = (const float*)d_in[2];
  const float* mask = (const float*)d_in[3];
  const float* wq = (const float*)d_in[4];
  const float* wk = (const float*)d_in[5];
  const float* wv = (const float*)d_in[6];
  const float* wo = (const float*)d_in[7];
  const int* pos = (const int*)d_in[8];
  float* out = (float*)d_out;

  char* ws = (char*)d_ws;
  const size_t MB = 1024 * 1024;
  // Region reuse plan (peak 104 MiB):
  ushort* qb = (ushort*)(ws + 0 * MB);     // [0,32): qb -> Khb[0,8)+Vtb[8,16)
  ushort* Khb = (ushort*)(ws + 0 * MB);
  ushort* Vtb = (ushort*)(ws + 8 * MB);
  ushort* wqT = (ushort*)(ws + 32 * MB);   // [32,64): wqT -> wkvT[32,48) -> Ohb[32,64)
  ushort* wkvT = (ushort*)(ws + 32 * MB);
  ushort* Ohb = (ushort*)(ws + 32 * MB);
  ushort* Qhb = (ushort*)(ws + 64 * MB);   // [64,96): Qhb -> woT
  ushort* woT = (ushort*)(ws + 64 * MB);
  ushort* mbf = (ushort*)(ws + 96 * MB);   // [96,104)

  dim3 blk(256);
  cvt_f32_bf16<<<dim3(4096), blk, 0, stream>>>(mask, mbf, 1048576);
  cvt_f32_bf16<<<dim3(16384), blk, 0, stream>>>(query, qb, 4194304);

  transpose_cvt<<<dim3(64, 64), blk, 0, stream>>>(wq, wqT, 4096);
  // Q projection, scale + RoPE fused (256^2 8-wave pipeline)
  gemm256<1><<<dim3(16, 16), dim3(512), 0, stream>>>(
      qb, wqT, Qhb, nullptr, pos, 4096, 0.08838834764831845f);

  transpose_cvt<<<dim3(16, 64), blk, 0, stream>>>(wk, wkvT, 1024);
  transpose_cvt<<<dim3(16, 64), blk, 0, stream>>>(wv, wkvT + (size_t)1024 * 4096, 1024);
  // fused K+V projection (K gets RoPE; V written transposed)
  gemm_bt<4, true><<<dim3(16, 32), blk, 0, stream>>>(
      key, value, nullptr, wkvT, Khb, Vtb, nullptr, pos, 2048, 1.0f);

  attn_kernel<<<dim3(16, 32, 4), blk, 0, stream>>>(Qhb, Khb, Vtb, mbf, Ohb);

  transpose_cvt<<<dim3(64, 64), blk, 0, stream>>>(wo, woT, 4096);  // Qhb dead
  // output projection -> fp32 d_out (256^2 8-wave pipeline)
  gemm256<0><<<dim3(16, 16), dim3(512), 0, stream>>>(
      Ohb, woT, nullptr, out, pos, 4096, 1.0f);
}

// Round 7
// 905.953 us; speedup vs baseline: 1.3160x; 1.0150x over previous
//
#include <hip/hip_runtime.h>

// GQA attention forward. Inputs/outputs FP32 (per reference); internal compute
// bf16 MFMA. BS=4 SEQ=1024 DM=4096 HQ=32 HKV=8 D_K=DV=128.
// R10 = R9 + XCD-chunk block swizzle on BOTH GEMMs (T1). R9 counters showed
// the KV GEMM fetching 533 MB (ideal 145): the 16 bx-blocks sharing each fp32
// A-panel were round-robined over 8 XCDs -> 8x panel re-fetch per L2. The
// swizzle gives each XCD a contiguous run of by-panels (all bx), so each
// A-panel is fetched by exactly one XCD. Same fix applied to gemm256.

using ushort = unsigned short;
typedef __attribute__((ext_vector_type(8))) short short8;   // 8 bf16 (4 VGPRs)
typedef __attribute__((ext_vector_type(4))) short short4v;  // 4 bf16
typedef __attribute__((ext_vector_type(4))) float f32x4;    // MFMA C/D
typedef __attribute__((ext_vector_type(4))) unsigned int uint4v;

__device__ __forceinline__ ushort f2bf(float x) {  // RNE fp32->bf16
  unsigned int u = __float_as_uint(x);
  u += 0x7FFFu + ((u >> 16) & 1u);
  return (ushort)(u >> 16);
}
__device__ __forceinline__ float bf2f(ushort h) {
  return __uint_as_float(((unsigned int)h) << 16);
}
// RNE pack: lo -> bits[15:0], hi -> bits[31:16] (T12; no builtin on gfx950)
__device__ __forceinline__ unsigned int cvt_pk_bf16(float lo, float hi) {
  unsigned int r;
  asm("v_cvt_pk_bf16_f32 %0, %1, %2" : "=v"(r) : "v"(lo), "v"(hi));
  return r;
}

__device__ __forceinline__ void async_copy16(const void* g, void* l) {
  // LDS dest = wave-uniform base + lane*16 (pass uniform l).
  __builtin_amdgcn_global_load_lds((const __attribute__((address_space(1))) void*)g,
                                   (__attribute__((address_space(3))) void*)l, 16, 0, 0);
}

// ---------------------------------------------------------------------------
// fp32 -> bf16 elementwise, 4 elems/thread
// ---------------------------------------------------------------------------
__global__ __launch_bounds__(256)
void cvt_f32_bf16(const float* __restrict__ in, ushort* __restrict__ out, int n4) {
  const int i = blockIdx.x * 256 + threadIdx.x;
  if (i < n4) {
    const float4 f = ((const float4*)in)[i];
    short4v v;
    v[0] = (short)f2bf(f.x); v[1] = (short)f2bf(f.y);
    v[2] = (short)f2bf(f.z); v[3] = (short)f2bf(f.w);
    ((short4v*)out)[i] = v;
  }
}

// ---------------------------------------------------------------------------
// Weight transpose+convert: B fp32 [4096][N] -> Bt bf16 [N][4096]
// ---------------------------------------------------------------------------
__global__ __launch_bounds__(256)
void transpose_cvt(const float* __restrict__ B, ushort* __restrict__ Bt, int N) {
  __shared__ ushort t[64][72];  // +8 pad breaks bank conflicts
  const int n0 = blockIdx.x * 64, k0 = blockIdx.y * 64;
  const int tid = threadIdx.x;
  const int r = tid >> 3, c8 = (tid & 7) * 8;
#pragma unroll
  for (int p = 0; p < 2; p++) {
    const float* src = B + (size_t)(k0 + r + p * 32) * N + n0 + c8;
    const float4 f0 = *(const float4*)src;
    const float4 f1 = *(const float4*)(src + 4);
    ushort* d = &t[r + p * 32][c8];
    d[0] = f2bf(f0.x); d[1] = f2bf(f0.y); d[2] = f2bf(f0.z); d[3] = f2bf(f0.w);
    d[4] = f2bf(f1.x); d[5] = f2bf(f1.y); d[6] = f2bf(f1.z); d[7] = f2bf(f1.w);
  }
  __syncthreads();
#pragma unroll
  for (int p = 0; p < 2; p++) {
    const int n = r + p * 32;
    short8 o;
#pragma unroll
    for (int j = 0; j < 8; j++) o[j] = (short)t[c8 + j][n];
    *(short8*)(Bt + (size_t)(n0 + n) * 4096 + k0 + c8) = o;
  }
}

// ---------------------------------------------------------------------------
// gemm256: C = A[4096x4096] * Bt[Nx4096]^T, 256^2 tile, BK=64, 8 waves.
// (structure as R9; see phase/hazard analysis there). XCD swizzle added:
// grid (16,16) = 256 blocks; w = (L&7)*32 + (L>>3) gives each XCD 2 complete
// A-panels x all bx -> A-panel fetched by exactly one XCD.
// ---------------------------------------------------------------------------
template <int MQ>
__device__ __forceinline__ void read_afrag(const ushort* Ab, int arbase,
                                           const int (&kslot)[2], short8 (&af)[2][2]) {
#pragma unroll
  for (int f = 0; f < 2; f++)
#pragma unroll
    for (int kk = 0; kk < 2; kk++)
      af[f][kk] = *(const short8*)(Ab + MQ * 8192 + arbase + f * 1024 + kslot[kk]);
}
template <int NQ>
__device__ __forceinline__ void read_bfrag(const ushort* Bb, int brbase,
                                           const int (&kslot)[2], short8 (&bg)[4][2]) {
#pragma unroll
  for (int g = 0; g < 4; g++)
#pragma unroll
    for (int kk = 0; kk < 2; kk++)
      bg[g][kk] = *(const short8*)(Bb + NQ * 8192 + brbase + (g & 1) * 1024 +
                                   (g >> 1) * 4096 + kslot[kk]);
}
__device__ __forceinline__ void mma_quad(short8 (&af)[2][2], short8 (&bg)[4][2],
                                         f32x4 (&q)[2][4]) {
#pragma unroll
  for (int f = 0; f < 2; f++)
#pragma unroll
    for (int g = 0; g < 4; g++)
#pragma unroll
      for (int kk = 0; kk < 2; kk++)
        q[f][g] = __builtin_amdgcn_mfma_f32_16x16x32_bf16(af[f][kk], bg[g][kk],
                                                          q[f][g], 0, 0, 0);
}

template <int MODE>
__global__ __launch_bounds__(512, 2)
void gemm256(const ushort* __restrict__ A, const ushort* __restrict__ Bt,
             ushort* __restrict__ C, float* __restrict__ Cf,
             const int* __restrict__ posp, int N, float scale) {
  constexpr int K = 4096, NT = 64;
  __shared__ alignas(16) ushort lds[65536];  // 128 KB
  const int tid = threadIdx.x;
  const int wave = tid >> 6, lane = tid & 63;
  const int quad = lane >> 4, l16 = lane & 15;
  const int wr = wave & 3, wc = wave >> 2;
  // XCD-chunk swizzle (bijective: 256 blocks = 8 XCD * 32)
  const int L = blockIdx.y * 16 + blockIdx.x;
  const int w = (L & 7) * 32 + (L >> 3);
  const int bx = w & 15, by = w >> 4;
  const int m0 = by * 256, n0 = bx * 256;

  // staging: thread covers row srow (of 64) x slot tid&7; global chunk
  // pre-swizzled so LDS linear slot s holds chunk s^(row&7).
  const int srow = tid >> 3, schunk = (tid & 7) ^ ((tid >> 3) & 7);
  const ushort* gA = A + (size_t)(m0 + srow) * K + schunk * 8;
  const ushort* gB = Bt + (size_t)(n0 + srow) * K + schunk * 8;
  ushort* const stbase = lds + wave * 512;  // HW adds lane*16B

  const int sw = l16 & 7;
  const int kslot[2] = {(quad ^ sw) * 8, ((4 + quad) ^ sw) * 8};
  const int arbase = (wr * 32 + l16) * 64;
  const int brbase = (wc * 32 + l16) * 64;

  short8 af[2][2], bg[4][2];
  f32x4 acc[2][2][2][4] = {};

  auto STAGE = [&](int bufo, int isB, int half, int t) {
    const ushort* src = (isB ? gB : gA) + (size_t)(half * 128) * K + t * 64;
    ushort* dst = stbase + bufo + isB * 16384 + half * 8192;
    async_copy16(src, dst);                          // rows 0-63 of half
    async_copy16(src + (size_t)64 * K, dst + 4096);  // rows 64-127
  };

  // prologue: tile 0, issue order A-lo, B-lo, B-hi, A-hi (matches steady state)
  STAGE(0, 0, 0, 0);
  STAGE(0, 1, 0, 0);
  STAGE(0, 1, 1, 0);
  STAGE(0, 0, 1, 0);
  __asm__ volatile("s_waitcnt vmcnt(4)" ::: "memory");  // A-lo,B-lo landed
  __builtin_amdgcn_s_barrier();

  for (int t = 0; t < NT; ++t) {
    const int bo = (t & 1) << 15;
    const int bn = bo ^ 32768;
    const bool pf = (t + 1) < NT;
    const ushort* Ab = lds + bo;
    const ushort* Bb = lds + bo + 16384;

    // ---- phase 1: (Mq0,Nq0) ----
    read_afrag<0>(Ab, arbase, kslot, af);
    read_bfrag<0>(Bb, brbase, kslot, bg);
    if (pf) STAGE(bn, 0, 0, t + 1);  // A-lo(t+1)
    __asm__ volatile("s_waitcnt lgkmcnt(8)" ::: "memory");
    __builtin_amdgcn_s_barrier();
    __asm__ volatile("s_waitcnt lgkmcnt(0)" ::: "memory");
    __builtin_amdgcn_sched_barrier(0);
    __builtin_amdgcn_s_setprio(1);
    mma_quad(af, bg, acc[0][0]);
    __builtin_amdgcn_s_setprio(0);
    if (pf) {
      __asm__ volatile("s_waitcnt vmcnt(2)" ::: "memory");  // A-hi,B-hi(t) in
    } else {
      __asm__ volatile("s_waitcnt vmcnt(0)" ::: "memory");
    }
    __builtin_amdgcn_s_barrier();

    // ---- phase 2: (Mq1,Nq0), reuse bg ----
    read_afrag<1>(Ab, arbase, kslot, af);
    if (pf) STAGE(bn, 1, 0, t + 1);  // B-lo(t+1)
    __builtin_amdgcn_s_barrier();
    __asm__ volatile("s_waitcnt lgkmcnt(0)" ::: "memory");
    __builtin_amdgcn_sched_barrier(0);
    __builtin_amdgcn_s_setprio(1);
    mma_quad(af, bg, acc[1][0]);
    __builtin_amdgcn_s_setprio(0);
    __builtin_amdgcn_s_barrier();

    // ---- phase 3: (Mq1,Nq1), reuse af ----
    read_bfrag<1>(Bb, brbase, kslot, bg);
    if (pf) STAGE(bn, 1, 1, t + 1);  // B-hi(t+1)
    __builtin_amdgcn_s_barrier();
    __asm__ volatile("s_waitcnt lgkmcnt(0)" ::: "memory");
    __builtin_amdgcn_sched_barrier(0);
    __builtin_amdgcn_s_setprio(1);
    mma_quad(af, bg, acc[1][1]);
    __builtin_amdgcn_s_setprio(0);
    __builtin_amdgcn_s_barrier();

    // ---- phase 4: (Mq0,Nq1), re-read A-lo, reuse bg ----
    read_afrag<0>(Ab, arbase, kslot, af);
    if (pf) STAGE(bn, 0, 1, t + 1);  // A-hi(t+1)
    __builtin_amdgcn_s_barrier();
    __asm__ volatile("s_waitcnt lgkmcnt(0)" ::: "memory");
    __builtin_amdgcn_sched_barrier(0);
    __builtin_amdgcn_s_setprio(1);
    mma_quad(af, bg, acc[0][1]);
    __builtin_amdgcn_s_setprio(0);
    if (pf) {
      __asm__ volatile("s_waitcnt vmcnt(4)" ::: "memory");  // A-lo,B-lo(t+1) in
    }
    __builtin_amdgcn_s_barrier();
  }

  // ---------------- epilogue ----------------
  if constexpr (MODE == 0) {
#pragma unroll
    for (int Mq = 0; Mq < 2; Mq++)
#pragma unroll
      for (int Nq = 0; Nq < 2; Nq++)
#pragma unroll
        for (int f = 0; f < 2; f++)
#pragma unroll
          for (int g = 0; g < 4; g++) {
            const int m = m0 + Mq * 128 + wr * 32 + f * 16 + quad * 4;
            const int n = n0 + Nq * 128 + wc * 32 + (g & 1) * 16 +
                          (g >> 1) * 64 + l16;
#pragma unroll
            for (int rr = 0; rr < 4; rr++)
              Cf[(size_t)(m + rr) * N + n] = acc[Mq][Nq][f][g][rr] * scale;
          }
  } else {
    // RoPE epilogue: head h = bx*2 + Nq, d = wc*32+(g&1)*16+(g>>1)*64+l16
    const int pos0 = posp[0];
    constexpr float lgbase = -0.20762050593045983f;  // -log2(10000)/64
    float invf[2];
    invf[0] = exp2f((float)(wc * 32 + l16) * lgbase);
    invf[1] = exp2f((float)(wc * 32 + 16 + l16) * lgbase);
#pragma unroll
    for (int Mq = 0; Mq < 2; Mq++)
#pragma unroll
      for (int f = 0; f < 2; f++)
#pragma unroll
        for (int rr = 0; rr < 4; rr++) {
          const int m = m0 + Mq * 128 + wr * 32 + f * 16 + quad * 4 + rr;
          const int s = m & 1023, bb = m >> 10;
          const float p = (float)(s + pos0);
#pragma unroll
          for (int Nq = 0; Nq < 2; Nq++) {
            const int h = bx * 2 + Nq;
            ushort* row = C + (((size_t)bb * 32 + h) * 1024 + s) * 128;
#pragma unroll
            for (int g = 0; g < 2; g++) {
              float sn, cs;
              sincosf(p * invf[g], &sn, &cs);
              const float x1 = acc[Mq][Nq][f][g][rr] * scale;
              const float x2 = acc[Mq][Nq][f][g + 2][rr] * scale;
              const int dlo = wc * 32 + g * 16 + l16;
              row[dlo] = f2bf(x1 * cs - x2 * sn);
              row[dlo + 64] = f2bf(x2 * cs + x1 * sn);
            }
          }
        }
  }
}

// ---------------------------------------------------------------------------
// gemm_bt (R8 ping-pong) — fused KV projection only. Grid MUST be (16,32).
// XCD swizzle: 512 blocks; w = (L&7)*64 + (L>>3) gives each XCD 4 complete
// A-panels x all 16 bx -> each fp32 key/value panel fetched by one XCD.
// MODE 4 (AF32): fused KV; n0<1024 -> K bf16 [b][8][s][128] with RoPE;
//                n0>=1024 -> V^T bf16 [b][8][128][s]
// ---------------------------------------------------------------------------
template <int MODE, bool AF32>
__global__ __launch_bounds__(256, 2)
void gemm_bt(const float* __restrict__ Af, const float* __restrict__ A2f,
             const ushort* __restrict__ Abf, const ushort* __restrict__ Bt,
             ushort* __restrict__ C, ushort* __restrict__ C2,
             float* __restrict__ Cf, const int* __restrict__ posp,
             int N, float scale) {
  constexpr int K = 4096;
  __shared__ alignas(16) ushort As[2][128 * 32];
  __shared__ alignas(16) ushort Bs[2][128 * 32];
  const int tid = threadIdx.x;
  const int wave = tid >> 6, lane = tid & 63;
  const int quad = lane >> 4, l16 = lane & 15;
  // XCD-chunk swizzle (bijective: 512 blocks = 8 XCD * 64); grid (16,32).
  const int L = blockIdx.y * 16 + blockIdx.x;
  const int w = (L & 7) * 64 + (L >> 3);
  const int m0 = (w >> 4) * 128, n0 = (w & 15) * 128;
  const int wm = (wave & 1) * 64, wn2 = (wave >> 1) * 32;

  const size_t aoff = (size_t)(m0 + wave * 16 + (lane >> 2)) * K + (lane & 3) * 8;
  const float* gAf = nullptr;
  const ushort* gAb = nullptr;
  if constexpr (AF32) {
    const float* Ause = Af;
    if constexpr (MODE == 4) {
      if (n0 >= 1024) Ause = A2f;  // V half reads `value`
    }
    gAf = Ause + aoff;
  } else {
    gAb = Abf + aoff;
  }
  const ushort* gB = Bt + (size_t)(n0 + wave * 16 + (lane >> 2)) * K + (lane & 3) * 8;
  const int woff = wave * 512;  // wave-uniform LDS sub-base
  constexpr size_t rstep = (size_t)64 * K;

  f32x4 acc[4][4] = {};

  // ---- prologue: stage tile 0 into half 0 ----
  if constexpr (AF32) {
    const float4 a0 = *(const float4*)(gAf);
    const float4 a1 = *(const float4*)(gAf + 4);
    const float4 b0 = *(const float4*)(gAf + rstep);
    const float4 b1 = *(const float4*)(gAf + rstep + 4);
    uint4v v0, v1;
    v0[0] = cvt_pk_bf16(a0.x, a0.y); v0[1] = cvt_pk_bf16(a0.z, a0.w);
    v0[2] = cvt_pk_bf16(a1.x, a1.y); v0[3] = cvt_pk_bf16(a1.z, a1.w);
    v1[0] = cvt_pk_bf16(b0.x, b0.y); v1[1] = cvt_pk_bf16(b0.z, b0.w);
    v1[2] = cvt_pk_bf16(b1.x, b1.y); v1[3] = cvt_pk_bf16(b1.z, b1.w);
    *(uint4v*)(As[0] + woff + lane * 8) = v0;
    *(uint4v*)(As[0] + 2048 + woff + lane * 8) = v1;
  } else {
    async_copy16(gAb, As[0] + woff);
    async_copy16(gAb + rstep, As[0] + 2048 + woff);
  }
  async_copy16(gB, Bs[0] + woff);
  async_copy16(gB + rstep, Bs[0] + 2048 + woff);

  for (int kt = 0; kt < K; kt += 32) {
    const int cur = (kt >> 5) & 1;
    const int nxt = cur ^ 1;
    const bool pf = (kt + 32) < K;
    __syncthreads();  // tile kt staged & visible; prev reads of half nxt done

    // issue tile kt+1 staging (drained at next loop-top barrier)
    float4 a0, a1, b0, b1;
    if constexpr (AF32) {
      if (pf) {  // loads issued now; cvt+ds_write sunk below the MFMAs
        a0 = *(const float4*)(gAf + kt + 32);
        a1 = *(const float4*)(gAf + kt + 36);
        b0 = *(const float4*)(gAf + rstep + kt + 32);
        b1 = *(const float4*)(gAf + rstep + kt + 36);
      }
    } else {
      if (pf) {
        async_copy16(gAb + kt + 32, As[nxt] + woff);
        async_copy16(gAb + rstep + kt + 32, As[nxt] + 2048 + woff);
      }
    }
    if (pf) {
      async_copy16(gB + kt + 32, Bs[nxt] + woff);
      async_copy16(gB + rstep + kt + 32, Bs[nxt] + 2048 + woff);
    }

    short8 af[4], bfrag[4];
#pragma unroll
    for (int i = 0; i < 4; i++) {
      af[i] = *(const short8*)(As[cur] + (wm + i * 16 + l16) * 32 + quad * 8);
      bfrag[i] = *(const short8*)(
          Bs[cur] + (wn2 + (i & 1) * 16 + (i >> 1) * 64 + l16) * 32 + quad * 8);
    }
    __builtin_amdgcn_s_setprio(1);
#pragma unroll
    for (int i = 0; i < 4; i++)
#pragma unroll
      for (int j = 0; j < 4; j++)
        acc[i][j] = __builtin_amdgcn_mfma_f32_16x16x32_bf16(af[i], bfrag[j],
                                                            acc[i][j], 0, 0, 0);
    __builtin_amdgcn_s_setprio(0);

    if constexpr (AF32) {
      if (pf) {  // A-load latency hidden under the MFMA cluster above
        uint4v v0, v1;
        v0[0] = cvt_pk_bf16(a0.x, a0.y); v0[1] = cvt_pk_bf16(a0.z, a0.w);
        v0[2] = cvt_pk_bf16(a1.x, a1.y); v0[3] = cvt_pk_bf16(a1.z, a1.w);
        v1[0] = cvt_pk_bf16(b0.x, b0.y); v1[1] = cvt_pk_bf16(b0.z, b0.w);
        v1[2] = cvt_pk_bf16(b1.x, b1.y); v1[3] = cvt_pk_bf16(b1.z, b1.w);
        *(uint4v*)(As[nxt] + woff + lane * 8) = v0;
        *(uint4v*)(As[nxt] + 2048 + woff + lane * 8) = v1;
      }
    }
  }

  // ---------------- epilogue ----------------
  if constexpr (MODE == 0) {
#pragma unroll
    for (int i = 0; i < 4; i++)
#pragma unroll
      for (int j = 0; j < 4; j++) {
        const int n = n0 + wn2 + (j & 1) * 16 + (j >> 1) * 64 + l16;
        const int mb = m0 + wm + i * 16 + quad * 4;
#pragma unroll
        for (int r = 0; r < 4; r++)
          Cf[(size_t)(mb + r) * N + n] = acc[i][j][r] * scale;
      }
  } else {
    const bool kv_v = (MODE == 4) && (n0 >= 1024);
    if (!kv_v) {
      // RoPE epilogue (K: MODE 4 low half)
      const int pos0 = posp[0];
      const int h = n0 >> 7;
      const int NH = (MODE == 1) ? 32 : 8;
      constexpr float lgbase = -0.20762050593045983f;  // -log2(10000)/64
      float invf[2];
      invf[0] = exp2f((float)(wn2 + l16) * lgbase);
      invf[1] = exp2f((float)(wn2 + 16 + l16) * lgbase);
#pragma unroll
      for (int i = 0; i < 4; i++) {
#pragma unroll
        for (int r = 0; r < 4; r++) {
          const int m = m0 + wm + i * 16 + quad * 4 + r;
          const int s = m & 1023, bb = m >> 10;
          const float p = (float)(s + pos0);
          ushort* row = C + (((size_t)bb * NH + h) * 1024 + s) * 128;
#pragma unroll
          for (int jj = 0; jj < 2; jj++) {
            float sn, cs;
            sincosf(p * invf[jj], &sn, &cs);
            const float x1 = acc[i][jj][r] * scale;
            const float x2 = acc[i][jj + 2][r] * scale;
            const int dlo = wn2 + jj * 16 + l16;
            row[dlo] = f2bf(x1 * cs - x2 * sn);
            row[dlo + 64] = f2bf(x2 * cs + x1 * sn);
          }
        }
      }
    } else {
      // V half: no RoPE, transposed write [b][8][128][s]
      const int hh = (n0 - 1024) >> 7;
#pragma unroll
      for (int i = 0; i < 4; i++)
#pragma unroll
        for (int j = 0; j < 4; j++) {
          const int d = wn2 + (j & 1) * 16 + (j >> 1) * 64 + l16;
          const int mb = m0 + wm + i * 16 + quad * 4;
#pragma unroll
          for (int r = 0; r < 4; r++) {
            const int m = mb + r;
            const int bb = m >> 10, s = m & 1023;
            C2[(((size_t)bb * 8 + hh) * 128 + d) * 1024 + s] = f2bf(acc[i][j][r]);
          }
        }
    }
  }
}

// ---------------------------------------------------------------------------
// Flash attention (unchanged from R7).
// ---------------------------------------------------------------------------
__global__ __launch_bounds__(256, 2)
void attn_kernel(const ushort* __restrict__ Qh, const ushort* __restrict__ Kh,
                 const ushort* __restrict__ Vt, const ushort* __restrict__ Mk,
                 ushort* __restrict__ Oh) {
  __shared__ alignas(16) ushort smem[36864];  // 72 KB
  ushort* const Ks0 = smem;
  ushort* const Ks1 = smem + 8192;
  ushort* const Vs0 = smem + 16384;
  ushort* const Vs1 = smem + 24576;
  ushort* const Ps = smem + 32768;   // 4 waves x 16x64 = 4096 ushorts (8 KB)
  ushort* const Qtmp = smem + 16384;  // overlays Vs0 (8192 ushorts), pre-loop only

  // XCD-chunked swizzle (bijective: 2048 = 8 * 256)
  int bid = (blockIdx.z * 32 + blockIdx.y) * 16 + blockIdx.x;
  bid = (bid & 7) * 256 + (bid >> 3);
  const int b = bid >> 9, h = (bid >> 4) & 31;
  const int q0 = (bid & 15) * 64;
  const int hkv = h >> 2;
  const int tid = threadIdx.x;
  const int wave = tid >> 6, lane = tid & 63;
  const int quad = lane >> 4, l16 = lane & 15;
  const int vr = lane >> 3;
  const int vkc = (lane & 7) ^ (vr & 7);

  const ushort* Qg = Qh + (((size_t)b * 32 + h) * 1024 + q0) * 128;
  const ushort* Kg = Kh + ((size_t)b * 8 + hkv) * (size_t)(1024 * 128);
  const ushort* Vg = Vt + ((size_t)b * 8 + hkv) * (size_t)(128 * 1024);
  const ushort* Mg = Mk + ((size_t)b * 1024 + q0) * 1024;

  // ---- prologue: stage Q (64x128) + K(0); hoist Q to registers ----
#pragma unroll
  for (int c = 0; c < 4; c++) {  // Q, swizzled: chunk j of row r at slot j^(r&15)
    const int i = wave * 4 + c;
    const int row = i * 4 + quad;
    const int kc = l16 ^ (c * 4 + quad);  // c*4+quad == row&15
    async_copy16(Qg + (size_t)row * 128 + kc * 8, Qtmp + i * 512);
  }
#pragma unroll
  for (int c = 0; c < 4; c++) {  // K(0) 64x128 -> Ks0, same swizzle
    const int i = wave * 4 + c;
    const int row = i * 4 + quad;
    const int kc = l16 ^ (c * 4 + quad);
    async_copy16(Kg + (size_t)row * 128 + kc * 8, Ks0 + i * 512);
  }
  __asm__ volatile("s_waitcnt vmcnt(0)" ::: "memory");  // own Q rows landed
  short8 qreg[4];
#pragma unroll
  for (int ks = 0; ks < 4; ks++)
    qreg[ks] = *(const short8*)(Qtmp + (size_t)(wave * 16 + l16) * 128 +
                                (((ks * 4 + quad) ^ l16) * 8));
  __syncthreads();  // all waves done with Qtmp before V0 staging overwrites it
#pragma unroll
  for (int c = 0; c < 4; c++) {  // V(0) 128x64 (V^T layout) -> Vs0
    const int i = wave * 4 + c;
    async_copy16(Vg + (size_t)(i * 8 + vr) * 1024 + vkc * 8, Vs0 + i * 512);
  }

  float m_i[4], l_p[4];
#pragma unroll
  for (int r = 0; r < 4; r++) { m_i[r] = -1e30f; l_p[r] = 0.0f; }
  f32x4 acc[8] = {};

  ushort* const PW = Ps + wave * 1024;  // 16 rows x 64 cols bf16, XOR-swizzled

  for (int kt = 0; kt < 1024; kt += 64) {
    const int it = kt >> 6;
    ushort* const Kc = (it & 1) ? Ks1 : Ks0;
    ushort* const Vc = (it & 1) ? Vs1 : Vs0;
    ushort* const Kn = (it & 1) ? Ks0 : Ks1;
    ushort* const Vn = (it & 1) ? Vs0 : Vs1;
    __syncthreads();  // single barrier: staged tile kt now visible everywhere

    // mask loads for this tile -> registers (consumed after QK; latency hidden)
    ushort mr[4][4];
#pragma unroll
    for (int nt = 0; nt < 4; nt++)
#pragma unroll
      for (int r = 0; r < 4; r++)
        mr[nt][r] = Mg[(size_t)(wave * 16 + quad * 4 + r) * 1024 +
                       kt + nt * 16 + l16];

    // S = Q K^T
    f32x4 s[4] = {};
    __builtin_amdgcn_s_setprio(1);
#pragma unroll
    for (int ks = 0; ks < 4; ks++) {
      const int ko = ((ks * 4 + quad) ^ l16) * 8;
#pragma unroll
      for (int nt = 0; nt < 4; nt++) {
        const short8 bk = *(const short8*)(Kc + (size_t)(nt * 16 + l16) * 128 + ko);
        s[nt] = __builtin_amdgcn_mfma_f32_16x16x32_bf16(qreg[ks], bk, s[nt], 0, 0, 0);
      }
    }
    __builtin_amdgcn_s_setprio(0);

    // issue next tile's staging into the ping-pong buffers (drained at next
    // loop-top barrier; overlaps softmax+PV below)
    if (kt < 960) {
#pragma unroll
      for (int c = 0; c < 4; c++) {
        const int i = wave * 4 + c;
        const int row = i * 4 + quad;
        const int kc = l16 ^ (c * 4 + quad);
        async_copy16(Kg + (size_t)(kt + 64 + row) * 128 + kc * 8, Kn + i * 512);
      }
#pragma unroll
      for (int c = 0; c < 4; c++) {
        const int i = wave * 4 + c;
        async_copy16(Vg + (size_t)(i * 8 + vr) * 1024 + kt + 64 + vkc * 8, Vn + i * 512);
      }
    }

    // additive mask (C layout: row = quad*4+r, col = l16)
#pragma unroll
    for (int nt = 0; nt < 4; nt++)
#pragma unroll
      for (int r = 0; r < 4; r++) s[nt][r] += bf2f(mr[nt][r]);

    // row max (16-lane reduce) + defer-max vote
    float mx[4];
    int need = 0;
#pragma unroll
    for (int r = 0; r < 4; r++) {
      float v = fmaxf(fmaxf(s[0][r], s[1][r]), fmaxf(s[2][r], s[3][r]));
#pragma unroll
      for (int off = 1; off < 16; off <<= 1) v = fmaxf(v, __shfl_xor(v, off));
      mx[r] = v;
      need |= (v > m_i[r] + 8.0f) ? 1 : 0;
    }
    if (__any(need)) {  // rescale path (rare after warm-up: defer-max THR=8)
#pragma unroll
      for (int r = 0; r < 4; r++) {
        const float mnew = fmaxf(m_i[r], mx[r]);
        const float al = __expf(m_i[r] - mnew);
        m_i[r] = mnew;
        l_p[r] *= al;
#pragma unroll
        for (int dt = 0; dt < 8; dt++) acc[dt][r] *= al;
      }
    }

    // exp + per-lane partial row sums + P -> LDS via cvt_pk (conflict-free
    // swizzle, measured 0 in R4/R6).
#pragma unroll
    for (int r = 0; r < 4; r++) {
      const int prow = quad * 4 + r;
      const int key8 = ((prow >> 1) & 7) * 8;
      const float p0 = __expf(s[0][r] - m_i[r]);
      const float p1 = __expf(s[1][r] - m_i[r]);
      const float p2 = __expf(s[2][r] - m_i[r]);
      const float p3 = __expf(s[3][r] - m_i[r]);
      l_p[r] += (p0 + p1) + (p2 + p3);
      const unsigned int u01 = cvt_pk_bf16(p0, p1);
      const unsigned int u23 = cvt_pk_bf16(p2, p3);
      ushort* row = PW + prow * 64;
      row[l16 ^ key8] = (ushort)u01;
      row[(16 + l16) ^ key8] = (ushort)(u01 >> 16);
      row[(32 + l16) ^ key8] = (ushort)u23;
      row[(48 + l16) ^ key8] = (ushort)(u23 >> 16);
    }
    __asm__ volatile("s_waitcnt lgkmcnt(0)" ::: "memory");

    // O += P V (A: P[m=l16][k], B: V^T[d][k])
    __builtin_amdgcn_s_setprio(1);
#pragma unroll
    for (int kk = 0; kk < 2; kk++) {
      const int pslot = ((kk * 4 + quad) ^ (l16 >> 1)) * 8;  // key = (row>>1)&7
      const short8 ap = *(const short8*)(PW + (size_t)l16 * 64 + pslot);
#pragma unroll
      for (int dt = 0; dt < 8; dt++) {
        const int vo = ((kk * 4 + quad) ^ (l16 & 7)) * 8;
        const short8 bv = *(const short8*)(Vc + (size_t)(dt * 16 + l16) * 64 + vo);
        acc[dt] = __builtin_amdgcn_mfma_f32_16x16x32_bf16(ap, bv, acc[dt], 0, 0, 0);
      }
    }
    __builtin_amdgcn_s_setprio(0);
  }

  // epilogue: finish deferred l reduce, normalize, store Oh[b*1024+s][h*128+d]
  ushort* Og = Oh + ((size_t)b * 1024 + q0 + wave * 16) * 4096 + h * 128;
#pragma unroll
  for (int r = 0; r < 4; r++) {
    float l = l_p[r];
#pragma unroll
    for (int off = 1; off < 16; off <<= 1) l += __shfl_xor(l, off);
    const float inv = 1.0f / l;
#pragma unroll
    for (int dt = 0; dt < 8; dt++)
      Og[(size_t)(quad * 4 + r) * 4096 + dt * 16 + l16] = f2bf(acc[dt][r] * inv);
  }
}

// ---------------------------------------------------------------------------
extern "C" void kernel_launch(void* const* d_in, const int* in_sizes, int n_in,
                              void* d_out, int out_size, void* d_ws, size_t ws_size,
                              hipStream_t stream) {
  (void)in_sizes; (void)n_in; (void)out_size; (void)ws_size;
  const float* query = (const float*)d_in[0];
  const float* key = (const float*)d_in[1];
  const float* value = (const float*)d_in[2];
  const float* mask = (const float*)d_in[3];
  const float* wq = (const float*)d_in[4];
  const float* wk = (const float*)d_in[5];
  const float* wv = (const float*)d_in[6];
  const float* wo = (const float*)d_in[7];
  const int* pos = (const int*)d_in[8];
  float* out = (float*)d_out;

  char* ws = (char*)d_ws;
  const size_t MB = 1024 * 1024;
  // Region reuse plan (peak 104 MiB):
  ushort* qb = (ushort*)(ws + 0 * MB);     // [0,32): qb -> Khb[0,8)+Vtb[8,16)
  ushort* Khb = (ushort*)(ws + 0 * MB);
  ushort* Vtb = (ushort*)(ws + 8 * MB);
  ushort* wqT = (ushort*)(ws + 32 * MB);   // [32,64): wqT -> wkvT[32,48) -> Ohb[32,64)
  ushort* wkvT = (ushort*)(ws + 32 * MB);
  ushort* Ohb = (ushort*)(ws + 32 * MB);
  ushort* Qhb = (ushort*)(ws + 64 * MB);   // [64,96): Qhb -> woT
  ushort* woT = (ushort*)(ws + 64 * MB);
  ushort* mbf = (ushort*)(ws + 96 * MB);   // [96,104)

  dim3 blk(256);
  cvt_f32_bf16<<<dim3(4096), blk, 0, stream>>>(mask, mbf, 1048576);
  cvt_f32_bf16<<<dim3(16384), blk, 0, stream>>>(query, qb, 4194304);

  transpose_cvt<<<dim3(64, 64), blk, 0, stream>>>(wq, wqT, 4096);
  // Q projection, scale + RoPE fused (256^2 8-wave pipeline)
  gemm256<1><<<dim3(16, 16), dim3(512), 0, stream>>>(
      qb, wqT, Qhb, nullptr, pos, 4096, 0.08838834764831845f);

  transpose_cvt<<<dim3(16, 64), blk, 0, stream>>>(wk, wkvT, 1024);
  transpose_cvt<<<dim3(16, 64), blk, 0, stream>>>(wv, wkvT + (size_t)1024 * 4096, 1024);
  // fused K+V projection (K gets RoPE; V written transposed)
  gemm_bt<4, true><<<dim3(16, 32), blk, 0, stream>>>(
      key, value, nullptr, wkvT, Khb, Vtb, nullptr, pos, 2048, 1.0f);

  attn_kernel<<<dim3(16, 32, 4), blk, 0, stream>>>(Qhb, Khb, Vtb, mbf, Ohb);

  transpose_cvt<<<dim3(64, 64), blk, 0, stream>>>(wo, woT, 4096);  // Qhb dead
  // output projection -> fp32 d_out (256^2 8-wave pipeline)
  gemm256<0><<<dim3(16, 16), dim3(512), 0, stream>>>(
      Ohb, woT, nullptr, out, pos, 4096, 1.0f);
}